// Round 1
// baseline (1377.287 us; speedup 1.0000x reference)
//
#include <hip/hip_runtime.h>

// Problem constants
#define NB 2
#define LL 2048
#define DD 1024
#define HH 16
#define DH 64
#define NHH (NB*HH)          // 32 (n,h) pairs
#define LT (LL/64)           // 32 tiles of 64
#define INV_SCALE (1.0f/32.0f)   // 1/sqrt(1024)

// ---------------------------------------------------------------------------
// K1: projections. block = one (n,l) row, 256 threads.
// thread t: d = t&63 (lane), handles heads h = (t>>6) + 4*i, i=0..3.
// W row (64 floats) kept in VGPRs; x read via wave-uniform float4 loads (L1).
// Outputs: qp/okp laid out [n][h][l][64]; vp/ovp natural [n][l][1024];
// ediag[n][h][l] = dot(q_proj, k_proj) (the samp_energy diagonal).
// kp is never materialized (only its diagonal dot is needed).
// ---------------------------------------------------------------------------
__global__ __launch_bounds__(256) void proj_kernel(
    const float* __restrict__ values, const float* __restrict__ keys,
    const float* __restrict__ query,  const float* __restrict__ ovals,
    const float* __restrict__ okeys,  const float* __restrict__ Wv,
    const float* __restrict__ Wk,     const float* __restrict__ Wq,
    float* __restrict__ qp, float* __restrict__ okp,
    float* __restrict__ vp, float* __restrict__ ovp,
    float* __restrict__ ediag)
{
    const int b = blockIdx.x;          // n*L + l
    const int n = b >> 11;             // /2048
    const int l = b & 2047;
    const int t = threadIdx.x;
    const int d = t & 63;
    const int h0 = t >> 6;             // 0..3 (wave id)
    const size_t rowoff = (size_t)b * DD;

    float wreg[64];

    auto load_w = [&](const float* W) {
        const float4* w4 = reinterpret_cast<const float4*>(W + d * 64);
#pragma unroll
        for (int e4 = 0; e4 < 16; ++e4) {
            float4 wv = w4[e4];
            wreg[4*e4+0] = wv.x; wreg[4*e4+1] = wv.y;
            wreg[4*e4+2] = wv.z; wreg[4*e4+3] = wv.w;
        }
    };

    auto proj_one = [&](const float* x, int h) -> float {
        const float4* x4 = reinterpret_cast<const float4*>(x + rowoff + h * 64);
        float a = 0.f;
#pragma unroll
        for (int e4 = 0; e4 < 16; ++e4) {
            float4 xv = x4[e4];
            a += xv.x * wreg[4*e4+0] + xv.y * wreg[4*e4+1]
               + xv.z * wreg[4*e4+2] + xv.w * wreg[4*e4+3];
        }
        return a;
    };

    float kacc[4], qacc[4];

    // keys (Wk) -> kacc (not stored)
    load_w(Wk);
#pragma unroll
    for (int i = 0; i < 4; ++i) kacc[i] = proj_one(keys, h0 + 4*i);

    // query (Wq) -> qacc, store qp
    load_w(Wq);
#pragma unroll
    for (int i = 0; i < 4; ++i) {
        int h = h0 + 4*i;
        qacc[i] = proj_one(query, h);
        qp[(((size_t)(n*HH + h)) * LL + l) * 64 + d] = qacc[i];
    }

    // ediag[n,h,l] = sum_d q*k  (full-wave reduce; all lanes share h)
#pragma unroll
    for (int i = 0; i < 4; ++i) {
        float p = qacc[i] * kacc[i];
        p += __shfl_down(p, 32); p += __shfl_down(p, 16);
        p += __shfl_down(p, 8);  p += __shfl_down(p, 4);
        p += __shfl_down(p, 2);  p += __shfl_down(p, 1);
        if ((t & 63) == 0) {
            int h = h0 + 4*i;
            ediag[((size_t)(n*HH + h)) * LL + l] = p;
        }
    }

    // values (Wv) -> vp ; origin_values (Wv) -> ovp
    load_w(Wv);
#pragma unroll
    for (int i = 0; i < 4; ++i) {
        int h = h0 + 4*i;
        vp[rowoff + h*64 + d]  = proj_one(values, h);
        ovp[rowoff + h*64 + d] = proj_one(ovals, h);
    }

    // origin_keys (Wk) -> okp
    load_w(Wk);
#pragma unroll
    for (int i = 0; i < 4; ++i) {
        int h = h0 + 4*i;
        okp[(((size_t)(n*HH + h)) * LL + l) * 64 + d] = proj_one(okeys, h);
    }
}

// ---------------------------------------------------------------------------
// K2: per-row softmax denominator Z_q (and diag score).
// block = (q-tile of 64 rows, nh). Loops k-tiles 0..qt. 64x64 energy tile
// via LDS-tiled dot products (stride 65 padding). No max-subtraction needed:
// logits/32 are O(1) for this data (std ~0.16).
// ---------------------------------------------------------------------------
__global__ __launch_bounds__(256) void zrow_kernel(
    const float* __restrict__ qp, const float* __restrict__ okp,
    const float* __restrict__ ediag,
    float* __restrict__ invZ, float* __restrict__ diag_s)
{
    __shared__ float Qs[64 * 65];
    __shared__ float Ks[64 * 65];
    __shared__ float eds[64];

    const int qt = blockIdx.x;
    const int nh = blockIdx.y;
    const int t  = threadIdx.x;
    const int tr = t >> 4;     // 0..15, owns rows tr*4..tr*4+3
    const int tc = t & 15;     // 0..15, owns cols tc*4..tc*4+3
    const size_t base = (size_t)nh * LL * 64;

    for (int idx = t; idx < 4096; idx += 256)
        Qs[(idx >> 6) * 65 + (idx & 63)] = qp[base + (size_t)qt * 4096 + idx];
    if (t < 64) eds[t] = ediag[(size_t)nh * LL + qt * 64 + t];

    float zacc[4] = {0.f, 0.f, 0.f, 0.f};

    for (int kt = 0; kt <= qt; ++kt) {
        __syncthreads();
        for (int idx = t; idx < 4096; idx += 256)
            Ks[(idx >> 6) * 65 + (idx & 63)] = okp[base + (size_t)kt * 4096 + idx];
        __syncthreads();

        float ev[4][4];
#pragma unroll
        for (int i = 0; i < 4; ++i)
#pragma unroll
            for (int j = 0; j < 4; ++j) ev[i][j] = 0.f;

#pragma unroll 8
        for (int e = 0; e < 64; ++e) {
            float a[4], bv[4];
#pragma unroll
            for (int i = 0; i < 4; ++i) a[i]  = Qs[(tr*4 + i) * 65 + e];
#pragma unroll
            for (int j = 0; j < 4; ++j) bv[j] = Ks[(tc*4 + j) * 65 + e];
#pragma unroll
            for (int i = 0; i < 4; ++i)
#pragma unroll
                for (int j = 0; j < 4; ++j) ev[i][j] += a[i] * bv[j];
        }

        if (kt < qt) {
#pragma unroll
            for (int i = 0; i < 4; ++i)
#pragma unroll
                for (int j = 0; j < 4; ++j)
                    zacc[i] += __expf(ev[i][j] * INV_SCALE);
        } else {  // edge tile: mask k>q, diagonal uses samp_energy
#pragma unroll
            for (int i = 0; i < 4; ++i) {
                int gq = qt*64 + tr*4 + i;
#pragma unroll
                for (int j = 0; j < 4; ++j) {
                    int gk = kt*64 + tc*4 + j;
                    if (gk > gq) continue;
                    float val = (gk == gq) ? eds[tr*4 + i] : ev[i][j];
                    zacc[i] += __expf(val * INV_SCALE);
                }
            }
        }
    }

    // reduce each row over its 16 column-owner lanes (contiguous in wave)
#pragma unroll
    for (int i = 0; i < 4; ++i) {
        float z = zacc[i];
        z += __shfl_down(z, 8); z += __shfl_down(z, 4);
        z += __shfl_down(z, 2); z += __shfl_down(z, 1);
        if (tc == 0) {
            int gq = qt*64 + tr*4 + i;
            float iz = 1.0f / z;
            invZ[(size_t)nh * LL + gq]   = iz;
            diag_s[(size_t)nh * LL + gq] = __expf(eds[tr*4 + i] * INV_SCALE) * iz;
        }
    }
}

// ---------------------------------------------------------------------------
// K3: colsum[l] = sum_{q>l} exp(e[q,l]/32) * invZ[q].
// block = (l-tile of 64 cols, nh). Loops q-tiles lt..LT-1.
// ---------------------------------------------------------------------------
__global__ __launch_bounds__(256) void colsum_kernel(
    const float* __restrict__ qp, const float* __restrict__ okp,
    const float* __restrict__ invZ, float* __restrict__ colsum)
{
    __shared__ float Ls[64 * 65];   // ok vectors of the 64 columns
    __shared__ float Qs[64 * 65];
    __shared__ float izs[64];
    __shared__ float cacc_s[64];

    const int lt = blockIdx.x;
    const int nh = blockIdx.y;
    const int t  = threadIdx.x;
    const int tr = t >> 4;   // q rows
    const int tc = t & 15;   // l cols
    const size_t base = (size_t)nh * LL * 64;

    for (int idx = t; idx < 4096; idx += 256)
        Ls[(idx >> 6) * 65 + (idx & 63)] = okp[base + (size_t)lt * 4096 + idx];
    if (t < 64) cacc_s[t] = 0.f;

    float cacc[4] = {0.f, 0.f, 0.f, 0.f};

    for (int qtile = lt; qtile < LT; ++qtile) {
        __syncthreads();
        for (int idx = t; idx < 4096; idx += 256)
            Qs[(idx >> 6) * 65 + (idx & 63)] = qp[base + (size_t)qtile * 4096 + idx];
        if (t < 64) izs[t] = invZ[(size_t)nh * LL + qtile * 64 + t];
        __syncthreads();

        float ev[4][4];
#pragma unroll
        for (int i = 0; i < 4; ++i)
#pragma unroll
            for (int j = 0; j < 4; ++j) ev[i][j] = 0.f;

#pragma unroll 8
        for (int e = 0; e < 64; ++e) {
            float a[4], bv[4];
#pragma unroll
            for (int i = 0; i < 4; ++i) a[i]  = Qs[(tr*4 + i) * 65 + e];
#pragma unroll
            for (int j = 0; j < 4; ++j) bv[j] = Ls[(tc*4 + j) * 65 + e];
#pragma unroll
            for (int i = 0; i < 4; ++i)
#pragma unroll
                for (int j = 0; j < 4; ++j) ev[i][j] += a[i] * bv[j];
        }

        if (qtile > lt) {
#pragma unroll
            for (int i = 0; i < 4; ++i) {
                float iz = izs[tr*4 + i];
#pragma unroll
                for (int j = 0; j < 4; ++j)
                    cacc[j] += __expf(ev[i][j] * INV_SCALE) * iz;
            }
        } else {  // edge tile: strictly q > l (diagonal excluded)
#pragma unroll
            for (int i = 0; i < 4; ++i) {
                int gq = qtile*64 + tr*4 + i;
                float iz = izs[tr*4 + i];
#pragma unroll
                for (int j = 0; j < 4; ++j) {
                    int gl = lt*64 + tc*4 + j;
                    if (gq > gl)
                        cacc[j] += __expf(ev[i][j] * INV_SCALE) * iz;
                }
            }
        }
    }

    __syncthreads();
#pragma unroll
    for (int j = 0; j < 4; ++j)
        atomicAdd(&cacc_s[tc*4 + j], cacc[j]);
    __syncthreads();
    if (t < 64)
        colsum[(size_t)nh * LL + lt * 64 + t] = cacc_s[t];
}

// ---------------------------------------------------------------------------
// K4: out[row,:] = (diag*vp + colsum*ovp) @ fc_w^T + fc_b, tiled GEMM.
// A tile built on the fly: i-tile index == head (D=16*64).
// ---------------------------------------------------------------------------
__global__ __launch_bounds__(256) void out_kernel(
    const float* __restrict__ vp, const float* __restrict__ ovp,
    const float* __restrict__ diag_s, const float* __restrict__ colsum,
    const float* __restrict__ fc_w, const float* __restrict__ fc_b,
    float* __restrict__ out)
{
    __shared__ float As[64 * 65];   // [row_local][i_local]
    __shared__ float Ws[64 * 65];   // [i_local][o_local]

    const int ot = blockIdx.x;   // 0..15  output tile
    const int rt = blockIdx.y;   // 0..63  row tile ((n,l) rows)
    const int t  = threadIdx.x;
    const int tr = t >> 4;
    const int tc = t & 15;

    float acc[4][4];
#pragma unroll
    for (int i = 0; i < 4; ++i)
#pragma unroll
        for (int j = 0; j < 4; ++j) acc[i][j] = 0.f;

    for (int it = 0; it < 16; ++it) {   // i-tile == head index
        __syncthreads();
        for (int idx = t; idx < 4096; idx += 256) {
            int lr = idx >> 6, ic = idx & 63;
            int row = rt*64 + lr;            // n*L + l
            int n = row >> 11, l = row & 2047;
            size_t nhl = ((size_t)(n*HH + it)) * LL + l;
            float dsc = diag_s[nhl];
            float csc = colsum[nhl];
            size_t gi = (size_t)row * DD + it*64 + ic;
            As[lr*65 + ic] = dsc * vp[gi] + csc * ovp[gi];
        }
        for (int idx = t; idx < 4096; idx += 256) {
            int oo = idx >> 6, ii = idx & 63;
            Ws[ii*65 + oo] = fc_w[(size_t)(ot*64 + oo) * DD + it*64 + ii];
        }
        __syncthreads();

#pragma unroll 8
        for (int e = 0; e < 64; ++e) {
            float a[4], bv[4];
#pragma unroll
            for (int i = 0; i < 4; ++i) a[i]  = As[(tr*4 + i) * 65 + e];
#pragma unroll
            for (int j = 0; j < 4; ++j) bv[j] = Ws[e*65 + tc*4 + j];
#pragma unroll
            for (int i = 0; i < 4; ++i)
#pragma unroll
                for (int j = 0; j < 4; ++j) acc[i][j] += a[i] * bv[j];
        }
    }

#pragma unroll
    for (int i = 0; i < 4; ++i) {
        int row = rt*64 + tr*4 + i;
#pragma unroll
        for (int j = 0; j < 4; ++j) {
            int o = ot*64 + tc*4 + j;
            out[(size_t)row * DD + o] = acc[i][j] + fc_b[o];
        }
    }
}

// ---------------------------------------------------------------------------
extern "C" void kernel_launch(void* const* d_in, const int* in_sizes, int n_in,
                              void* d_out, int out_size, void* d_ws, size_t ws_size,
                              hipStream_t stream) {
    const float* values = (const float*)d_in[0];
    const float* keys   = (const float*)d_in[1];
    const float* query  = (const float*)d_in[2];
    const float* ovals  = (const float*)d_in[3];
    const float* okeys  = (const float*)d_in[4];
    const float* Wv     = (const float*)d_in[5];
    const float* Wk     = (const float*)d_in[6];
    const float* Wq     = (const float*)d_in[7];
    const float* fc_w   = (const float*)d_in[8];
    const float* fc_b   = (const float*)d_in[9];
    // d_in[10] is the mask; HIST==L makes it pure-causal, handled analytically.
    float* out = (float*)d_out;

    float* ws     = (float*)d_ws;
    float* qp     = ws;                  // [32][2048][64]
    float* okp    = qp  + 4194304;       // [32][2048][64]
    float* vp     = okp + 4194304;       // [2][2048][1024]
    float* ovp    = vp  + 4194304;       // [2][2048][1024]
    float* ediag  = ovp + 4194304;       // [32][2048]
    float* invZ   = ediag + 65536;
    float* diag_s = invZ  + 65536;
    float* colsum = diag_s + 65536;
    // total ws use: 4*4194304 + 4*65536 floats = 68.2 MB

    proj_kernel<<<dim3(NB * LL), 256, 0, stream>>>(
        values, keys, query, ovals, okeys, Wv, Wk, Wq, qp, okp, vp, ovp, ediag);
    zrow_kernel<<<dim3(LT, NHH), 256, 0, stream>>>(qp, okp, ediag, invZ, diag_s);
    colsum_kernel<<<dim3(LT, NHH), 256, 0, stream>>>(qp, okp, invZ, colsum);
    out_kernel<<<dim3(16, 64), 256, 0, stream>>>(vp, ovp, diag_s, colsum, fc_w, fc_b, out);
}

// Round 2
// 706.258 us; speedup vs baseline: 1.9501x; 1.9501x over previous
//
#include <hip/hip_runtime.h>

// Problem constants
#define NB 2
#define LL 2048
#define DD 1024
#define HH 16
#define NHH (NB*HH)          // 32 (n,h) pairs
#define LT (LL/64)           // 32 tiles of 64
#define CEXP 0.0450842200277801f   // log2(e)/32 : exp(x/32) == exp2(x*CEXP)

typedef __bf16 bf16x8 __attribute__((ext_vector_type(8)));
typedef float f32x4 __attribute__((ext_vector_type(4)));

__device__ __forceinline__ unsigned short f2bf(float f) {
    unsigned u = __float_as_uint(f);
    return (unsigned short)((u + 0x7fffu + ((u >> 16) & 1u)) >> 16);   // RNE
}
__device__ __forceinline__ bf16x8 ldfrag(const unsigned short* p) {
    return *reinterpret_cast<const bf16x8*>(p);
}

// ---------------------------------------------------------------------------
// K1: projections. block = one (n,l) row, 256 threads.
// thread t: d = t&63 (lane), handles heads h = (t>>6) + 4*i, i=0..3.
// Outputs: qb/okb bf16 laid out [nh][l][64] (MFMA operands);
// vp/ovp fp32 natural [n][l][1024]; ediag fp32 (diag uses full precision).
// ---------------------------------------------------------------------------
__global__ __launch_bounds__(256) void proj_kernel(
    const float* __restrict__ values, const float* __restrict__ keys,
    const float* __restrict__ query,  const float* __restrict__ ovals,
    const float* __restrict__ okeys,  const float* __restrict__ Wv,
    const float* __restrict__ Wk,     const float* __restrict__ Wq,
    unsigned short* __restrict__ qb, unsigned short* __restrict__ okb,
    float* __restrict__ vp, float* __restrict__ ovp,
    float* __restrict__ ediag)
{
    const int b = blockIdx.x;          // n*L + l
    const int n = b >> 11;
    const int l = b & 2047;
    const int t = threadIdx.x;
    const int d = t & 63;
    const int h0 = t >> 6;             // 0..3 (wave id)
    const size_t rowoff = (size_t)b * DD;

    float wreg[64];

    auto load_w = [&](const float* W) {
        const float4* w4 = reinterpret_cast<const float4*>(W + d * 64);
#pragma unroll
        for (int e4 = 0; e4 < 16; ++e4) {
            float4 wv = w4[e4];
            wreg[4*e4+0] = wv.x; wreg[4*e4+1] = wv.y;
            wreg[4*e4+2] = wv.z; wreg[4*e4+3] = wv.w;
        }
    };

    auto proj_one = [&](const float* x, int h) -> float {
        const float4* x4 = reinterpret_cast<const float4*>(x + rowoff + h * 64);
        float a = 0.f;
#pragma unroll
        for (int e4 = 0; e4 < 16; ++e4) {
            float4 xv = x4[e4];
            a += xv.x * wreg[4*e4+0] + xv.y * wreg[4*e4+1]
               + xv.z * wreg[4*e4+2] + xv.w * wreg[4*e4+3];
        }
        return a;
    };

    float kacc[4], qacc[4];

    load_w(Wk);
#pragma unroll
    for (int i = 0; i < 4; ++i) kacc[i] = proj_one(keys, h0 + 4*i);

    load_w(Wq);
#pragma unroll
    for (int i = 0; i < 4; ++i) {
        int h = h0 + 4*i;
        qacc[i] = proj_one(query, h);
        qb[(((size_t)(n*HH + h)) * LL + l) * 64 + d] = f2bf(qacc[i]);
    }

    // ediag[n,h,l] = sum_d q*k  (fp32, full-wave reduce)
#pragma unroll
    for (int i = 0; i < 4; ++i) {
        float p = qacc[i] * kacc[i];
        p += __shfl_down(p, 32); p += __shfl_down(p, 16);
        p += __shfl_down(p, 8);  p += __shfl_down(p, 4);
        p += __shfl_down(p, 2);  p += __shfl_down(p, 1);
        if (d == 0) {
            int h = h0 + 4*i;
            ediag[((size_t)(n*HH + h)) * LL + l] = p;
        }
    }

    load_w(Wv);
#pragma unroll
    for (int i = 0; i < 4; ++i) {
        int h = h0 + 4*i;
        vp[rowoff + h*64 + d]  = proj_one(values, h);
        ovp[rowoff + h*64 + d] = proj_one(ovals, h);
    }

    load_w(Wk);
#pragma unroll
    for (int i = 0; i < 4; ++i) {
        int h = h0 + 4*i;
        okb[(((size_t)(n*HH + h)) * LL + l) * 64 + d] = f2bf(proj_one(okeys, h));
    }
}

// ---------------------------------------------------------------------------
// K2: per-row softmax denominator Z_q (and diag score) via MFMA.
// Block = (q-tile of 64 rows, nh); 4 waves, wave w owns rows qt*64+w*16..+15.
// Q frags held in registers for the whole k-loop; OK frags loaded per tile.
// E tile 16x16 via 2x mfma_f32_16x16x32_bf16; exp/mask in fp32.
// No LDS; logits/32 are O(1) so no max-subtraction needed.
// ---------------------------------------------------------------------------
__global__ __launch_bounds__(256) void zrow_kernel(
    const unsigned short* __restrict__ qb, const unsigned short* __restrict__ okb,
    const float* __restrict__ ediag,
    float* __restrict__ invZ, float* __restrict__ diag_s)
{
    const int qt = blockIdx.x;
    const int nh = blockIdx.y;
    const int t = threadIdx.x;
    const int w = t >> 6;
    const int lane = t & 63;
    const int n = lane & 15;          // MFMA col / frag row
    const int quad = lane >> 4;       // frag k-offset group
    const size_t base = (size_t)nh * (LL * 64);
    const size_t nhL = (size_t)nh * LL;
    const int qrow0 = qt * 64 + w * 16;

    const unsigned short* qrow = qb + base + (size_t)(qrow0 + n) * 64 + quad * 8;
    bf16x8 aq0 = ldfrag(qrow);
    bf16x8 aq1 = ldfrag(qrow + 32);

    float zacc[4] = {0.f, 0.f, 0.f, 0.f};
    const int ntk = qrow0 >> 4;       // full (unmasked) 16-col tiles

    for (int kt = 0; kt < ntk; ++kt) {
        const unsigned short* kp = okb + base + (size_t)(kt * 16 + n) * 64 + quad * 8;
        bf16x8 b0 = ldfrag(kp);
        bf16x8 b1 = ldfrag(kp + 32);
        f32x4 d = {0.f, 0.f, 0.f, 0.f};
        d = __builtin_amdgcn_mfma_f32_16x16x32_bf16(aq0, b0, d, 0, 0, 0);
        d = __builtin_amdgcn_mfma_f32_16x16x32_bf16(aq1, b1, d, 0, 0, 0);
#pragma unroll
        for (int r = 0; r < 4; ++r) zacc[r] += exp2f(d[r] * CEXP);
    }
    {   // edge tile: k-cols == own rows; include strictly causal (gk < gq)
        const unsigned short* kp = okb + base + (size_t)(qrow0 + n) * 64 + quad * 8;
        bf16x8 b0 = ldfrag(kp);
        bf16x8 b1 = ldfrag(kp + 32);
        f32x4 d = {0.f, 0.f, 0.f, 0.f};
        d = __builtin_amdgcn_mfma_f32_16x16x32_bf16(aq0, b0, d, 0, 0, 0);
        d = __builtin_amdgcn_mfma_f32_16x16x32_bf16(aq1, b1, d, 0, 0, 0);
#pragma unroll
        for (int r = 0; r < 4; ++r)
            if (n < quad * 4 + r) zacc[r] += exp2f(d[r] * CEXP);
    }

    // reduce over the 16 column lanes of each quad; add diagonal term
#pragma unroll
    for (int r = 0; r < 4; ++r) {
        float z = zacc[r];
        z += __shfl_xor(z, 1); z += __shfl_xor(z, 2);
        z += __shfl_xor(z, 4); z += __shfl_xor(z, 8);
        if (n == 0) {
            int gq = qrow0 + quad * 4 + r;
            float de = exp2f(ediag[nhL + gq] * CEXP);
            float iz = 1.f / (z + de);
            invZ[nhL + gq]   = iz;
            diag_s[nhL + gq] = de * iz;
        }
    }
}

// ---------------------------------------------------------------------------
// K3: colsum[l] = sum_{q>l} exp(e[q,l]/32) * invZ[q], via MFMA.
// Block = (l-tile of 64 cols, nh); wave w owns cols lt*64+w*16..+15 (B frags
// in registers), loops q-16-tiles upward. invZ broadcast via __shfl.
// ---------------------------------------------------------------------------
__global__ __launch_bounds__(256) void colsum_kernel(
    const unsigned short* __restrict__ qb, const unsigned short* __restrict__ okb,
    const float* __restrict__ invZ, float* __restrict__ colsum)
{
    const int lt = blockIdx.x;
    const int nh = blockIdx.y;
    const int t = threadIdx.x;
    const int w = t >> 6;
    const int lane = t & 63;
    const int n = lane & 15;
    const int quad = lane >> 4;
    const size_t base = (size_t)nh * (LL * 64);
    const size_t nhL = (size_t)nh * LL;
    const int lrow0 = lt * 64 + w * 16;

    const unsigned short* lrow = okb + base + (size_t)(lrow0 + n) * 64 + quad * 8;
    bf16x8 bl0 = ldfrag(lrow);
    bf16x8 bl1 = ldfrag(lrow + 32);

    float cacc = 0.f;
    const int qt0 = lrow0 >> 4;

    {   // diagonal-overlap tile: q rows == own cols; include gq > gl (m > n)
        const unsigned short* qp_ = qb + base + (size_t)(lrow0 + n) * 64 + quad * 8;
        bf16x8 a0 = ldfrag(qp_);
        bf16x8 a1 = ldfrag(qp_ + 32);
        f32x4 d = {0.f, 0.f, 0.f, 0.f};
        d = __builtin_amdgcn_mfma_f32_16x16x32_bf16(a0, bl0, d, 0, 0, 0);
        d = __builtin_amdgcn_mfma_f32_16x16x32_bf16(a1, bl1, d, 0, 0, 0);
        float izq = invZ[nhL + lrow0 + n];
#pragma unroll
        for (int r = 0; r < 4; ++r) {
            int m = quad * 4 + r;
            float izr = __shfl(izq, m);
            if (m > n) cacc += exp2f(d[r] * CEXP) * izr;
        }
    }
    for (int qt = qt0 + 1; qt < LL / 16; ++qt) {
        const unsigned short* qp_ = qb + base + (size_t)(qt * 16 + n) * 64 + quad * 8;
        bf16x8 a0 = ldfrag(qp_);
        bf16x8 a1 = ldfrag(qp_ + 32);
        f32x4 d = {0.f, 0.f, 0.f, 0.f};
        d = __builtin_amdgcn_mfma_f32_16x16x32_bf16(a0, bl0, d, 0, 0, 0);
        d = __builtin_amdgcn_mfma_f32_16x16x32_bf16(a1, bl1, d, 0, 0, 0);
        float izq = invZ[nhL + qt * 16 + n];
#pragma unroll
        for (int r = 0; r < 4; ++r) {
            float izr = __shfl(izq, quad * 4 + r);
            cacc += exp2f(d[r] * CEXP) * izr;
        }
    }

    // reduce col-partials over the 4 quads; lanes 0..15 hold the 16 cols
    cacc += __shfl_down(cacc, 32);
    cacc += __shfl_down(cacc, 16);
    if (lane < 16) colsum[nhL + lrow0 + lane] = cacc;
}

// ---------------------------------------------------------------------------
// K4: fc_w -> bf16
// ---------------------------------------------------------------------------
__global__ __launch_bounds__(256) void fcw_kernel(
    const float* __restrict__ fc_w, unsigned short* __restrict__ fcwb)
{
    const int idx = blockIdx.x * 1024 + threadIdx.x * 4;
    float4 wv = *reinterpret_cast<const float4*>(fc_w + idx);
    ushort4 o;
    o.x = f2bf(wv.x); o.y = f2bf(wv.y); o.z = f2bf(wv.z); o.w = f2bf(wv.w);
    *reinterpret_cast<ushort4*>(fcwb + idx) = o;
}

// ---------------------------------------------------------------------------
// K5: attb[row][d] = bf16( diag_s*vp + colsum*ovp )
// ---------------------------------------------------------------------------
__global__ __launch_bounds__(256) void att_kernel(
    const float* __restrict__ vp, const float* __restrict__ ovp,
    const float* __restrict__ diag_s, const float* __restrict__ colsum,
    unsigned short* __restrict__ attb)
{
    const int row = blockIdx.x;            // n*L + l
    const int nn = row >> 11, l = row & 2047;
    const int t = threadIdx.x;
    const int d0 = t * 4;
    const int h = t >> 4;                  // d0>>6
    const size_t nhl = ((size_t)(nn * HH + h)) * LL + l;
    const float ds = diag_s[nhl];
    const float cs = colsum[nhl];
    const float4 v  = *reinterpret_cast<const float4*>(vp  + (size_t)row * DD + d0);
    const float4 ov = *reinterpret_cast<const float4*>(ovp + (size_t)row * DD + d0);
    ushort4 o;
    o.x = f2bf(ds * v.x + cs * ov.x);
    o.y = f2bf(ds * v.y + cs * ov.y);
    o.z = f2bf(ds * v.z + cs * ov.z);
    o.w = f2bf(ds * v.w + cs * ov.w);
    *reinterpret_cast<ushort4*>(attb + (size_t)row * DD + d0) = o;
}

// ---------------------------------------------------------------------------
// K6: out = attb @ fcwb^T + fc_b, bf16 MFMA GEMM. Block = 64x64 C tile,
// wave w owns rows w*16..+15 x all 64 cols (4 accumulators).
// ---------------------------------------------------------------------------
__global__ __launch_bounds__(256) void out_kernel(
    const unsigned short* __restrict__ attb, const unsigned short* __restrict__ fcwb,
    const float* __restrict__ fc_b, float* __restrict__ out)
{
    const int nt = blockIdx.x;   // 0..15 col tile
    const int mt = blockIdx.y;   // 0..63 row tile
    const int t = threadIdx.x;
    const int w = t >> 6;
    const int lane = t & 63;
    const int n = lane & 15;
    const int quad = lane >> 4;

    f32x4 acc[4];
#pragma unroll
    for (int j = 0; j < 4; ++j) acc[j] = (f32x4){0.f, 0.f, 0.f, 0.f};

    const unsigned short* ap = attb + (size_t)(mt * 64 + w * 16 + n) * DD + quad * 8;
    const unsigned short* bp = fcwb + (size_t)(nt * 64 + n) * DD + quad * 8;

    for (int kc = 0; kc < DD; kc += 32) {
        bf16x8 a = ldfrag(ap + kc);
#pragma unroll
        for (int j = 0; j < 4; ++j) {
            bf16x8 b = ldfrag(bp + (size_t)(j * 16) * DD + kc);
            acc[j] = __builtin_amdgcn_mfma_f32_16x16x32_bf16(a, b, acc[j], 0, 0, 0);
        }
    }

#pragma unroll
    for (int j = 0; j < 4; ++j) {
        const int col = nt * 64 + j * 16 + n;
        const float bias = fc_b[col];
#pragma unroll
        for (int r = 0; r < 4; ++r) {
            const int grow = mt * 64 + w * 16 + quad * 4 + r;
            out[(size_t)grow * DD + col] = acc[j][r] + bias;
        }
    }
}

// ---------------------------------------------------------------------------
extern "C" void kernel_launch(void* const* d_in, const int* in_sizes, int n_in,
                              void* d_out, int out_size, void* d_ws, size_t ws_size,
                              hipStream_t stream) {
    const float* values = (const float*)d_in[0];
    const float* keys   = (const float*)d_in[1];
    const float* query  = (const float*)d_in[2];
    const float* ovals  = (const float*)d_in[3];
    const float* okeys  = (const float*)d_in[4];
    const float* Wv     = (const float*)d_in[5];
    const float* Wk     = (const float*)d_in[6];
    const float* Wq     = (const float*)d_in[7];
    const float* fc_w   = (const float*)d_in[8];
    const float* fc_b   = (const float*)d_in[9];
    // d_in[10]: mask — HIST==L makes it pure causal, handled analytically.
    float* out = (float*)d_out;

    float* ws      = (float*)d_ws;
    float* vp      = ws;                    // 4194304 f32
    float* ovp     = vp + 4194304;          // 4194304 f32
    float* ediag   = ovp + 4194304;         // 65536 f32
    float* invZ    = ediag + 65536;
    float* diag_s  = invZ + 65536;
    float* colsum  = diag_s + 65536;
    unsigned short* qb   = (unsigned short*)(colsum + 65536);  // [32][2048][64] bf16
    unsigned short* okb  = qb + 4194304;
    unsigned short* attb = okb + 4194304;   // [4096][1024] bf16
    unsigned short* fcwb = attb + 4194304;  // [1024][1024] bf16
    // total ~62 MB

    proj_kernel<<<dim3(NB * LL), 256, 0, stream>>>(
        values, keys, query, ovals, okeys, Wv, Wk, Wq, qb, okb, vp, ovp, ediag);
    fcw_kernel<<<dim3(1024), 256, 0, stream>>>(fc_w, fcwb);
    zrow_kernel<<<dim3(LT, NHH), 256, 0, stream>>>(qb, okb, ediag, invZ, diag_s);
    colsum_kernel<<<dim3(LT, NHH), 256, 0, stream>>>(qb, okb, invZ, colsum);
    att_kernel<<<dim3(NB * LL), 256, 0, stream>>>(vp, ovp, diag_s, colsum, attb);
    out_kernel<<<dim3(16, 64), 256, 0, stream>>>(attb, fcwb, fc_b, out);
}

// Round 3
// 339.400 us; speedup vs baseline: 4.0580x; 2.0809x over previous
//
#include <hip/hip_runtime.h>

// Problem constants
#define NB 2
#define LL 2048
#define DD 1024
#define HH 16
#define NHH (NB*HH)          // 32 (n,h) pairs
#define LT (LL/64)           // 32 tiles of 64
#define KT16 (LL/16)         // 128 16-col tiles
#define CEXP 0.0450842200277801f   // log2(e)/32 : exp(x/32) == exp2(x*CEXP)

typedef __bf16 bf16x8 __attribute__((ext_vector_type(8)));
typedef unsigned short u16x8 __attribute__((ext_vector_type(8)));
typedef float f32x4 __attribute__((ext_vector_type(4)));

__device__ __forceinline__ unsigned short f2bf(float f) {
    unsigned u = __float_as_uint(f);
    return (unsigned short)((u + 0x7fffu + ((u >> 16) & 1u)) >> 16);   // RNE
}
__device__ __forceinline__ float bf2f(unsigned short u) {
    return __uint_as_float(((unsigned)u) << 16);
}
__device__ __forceinline__ bf16x8 ldfrag(const unsigned short* p) {
    return *reinterpret_cast<const bf16x8*>(p);
}
// 8 consecutive fp32 -> bf16x8 fragment
__device__ __forceinline__ bf16x8 cvt8(const float* p) {
    float4 a = *reinterpret_cast<const float4*>(p);
    float4 b = *reinterpret_cast<const float4*>(p + 4);
    u16x8 u;
    u[0]=f2bf(a.x); u[1]=f2bf(a.y); u[2]=f2bf(a.z); u[3]=f2bf(a.w);
    u[4]=f2bf(b.x); u[5]=f2bf(b.y); u[6]=f2bf(b.z); u[7]=f2bf(b.w);
    return __builtin_bit_cast(bf16x8, u);
}

// ---------------------------------------------------------------------------
// K1: projections via MFMA. Block = 64 rows x 2 heads; 4 waves, wave w owns
// rows rb+w*16..+15 for both heads, all 5 inputs. W (64x64, head-shared)
// held as 8 B-frags per matrix in VGPRs. ediag from q/k C-frags.
// Outputs: qb/okb bf16 [nh][l][64]; vb/ovb bf16 natural [n][l][1024];
// ediag fp32 [nh][l].
// ---------------------------------------------------------------------------
__global__ __launch_bounds__(256) void proj_kernel(
    const float* __restrict__ values, const float* __restrict__ keys,
    const float* __restrict__ query,  const float* __restrict__ ovals,
    const float* __restrict__ okeys,  const float* __restrict__ Wv,
    const float* __restrict__ Wk,     const float* __restrict__ Wq,
    unsigned short* __restrict__ qb, unsigned short* __restrict__ okb,
    unsigned short* __restrict__ vb, unsigned short* __restrict__ ovb,
    float* __restrict__ ediag)
{
    const int rb = blockIdx.x * 64;     // row base in (n*L+l) space
    const int h0 = blockIdx.y * 2;      // first of 2 heads
    const int t = threadIdx.x;
    const int w = t >> 6;
    const int lane = t & 63;
    const int n16 = lane & 15;
    const int quad = lane >> 4;
    const int arow = rb + w * 16 + n16;       // A-frag source row
    const int orow = rb + w * 16 + quad * 4;  // C-frag row base (+r)
    const int onb = orow >> 11;
    const int olb = orow & 2047;

    // B frags: W[j*16+n16][quad*8 ...]
    bf16x8 wk0[4], wk1[4], wq0[4], wq1[4];
#pragma unroll
    for (int j = 0; j < 4; ++j) {
        const float* p = Wk + (j * 16 + n16) * 64 + quad * 8;
        wk0[j] = cvt8(p); wk1[j] = cvt8(p + 32);
        const float* q = Wq + (j * 16 + n16) * 64 + quad * 8;
        wq0[j] = cvt8(q); wq1[j] = cvt8(q + 32);
    }

#pragma unroll
    for (int hh = 0; hh < 2; ++hh) {
        const int h = h0 + hh;
        const size_t aoff = (size_t)arow * DD + h * 64 + quad * 8;
        bf16x8 a0, a1;
        f32x4 ka[4], qa[4];

        a0 = cvt8(keys + aoff); a1 = cvt8(keys + aoff + 32);
#pragma unroll
        for (int j = 0; j < 4; ++j) {
            f32x4 d = {0.f,0.f,0.f,0.f};
            d = __builtin_amdgcn_mfma_f32_16x16x32_bf16(a0, wk0[j], d, 0,0,0);
            ka[j] = __builtin_amdgcn_mfma_f32_16x16x32_bf16(a1, wk1[j], d, 0,0,0);
        }
        a0 = cvt8(query + aoff); a1 = cvt8(query + aoff + 32);
#pragma unroll
        for (int j = 0; j < 4; ++j) {
            f32x4 d = {0.f,0.f,0.f,0.f};
            d = __builtin_amdgcn_mfma_f32_16x16x32_bf16(a0, wq0[j], d, 0,0,0);
            qa[j] = __builtin_amdgcn_mfma_f32_16x16x32_bf16(a1, wq1[j], d, 0,0,0);
        }
        // store q projection
        const size_t qbase = (((size_t)(onb * HH + h)) * LL + olb) * 64;
#pragma unroll
        for (int j = 0; j < 4; ++j)
#pragma unroll
            for (int r = 0; r < 4; ++r)
                qb[qbase + (size_t)r * 64 + j * 16 + n16] = f2bf(qa[j][r]);
        // ediag = rowwise dot(q,k): sum over j then over the 16 n-lanes
#pragma unroll
        for (int r = 0; r < 4; ++r) {
            float p = qa[0][r]*ka[0][r] + qa[1][r]*ka[1][r]
                    + qa[2][r]*ka[2][r] + qa[3][r]*ka[3][r];
            p += __shfl_xor(p, 1); p += __shfl_xor(p, 2);
            p += __shfl_xor(p, 4); p += __shfl_xor(p, 8);
            if (n16 == 0)
                ediag[((size_t)(onb * HH + h)) * LL + olb + r] = p;
        }
        // origin_keys projection (uses Wk)
        a0 = cvt8(okeys + aoff); a1 = cvt8(okeys + aoff + 32);
#pragma unroll
        for (int j = 0; j < 4; ++j) {
            f32x4 d = {0.f,0.f,0.f,0.f};
            d = __builtin_amdgcn_mfma_f32_16x16x32_bf16(a0, wk0[j], d, 0,0,0);
            d = __builtin_amdgcn_mfma_f32_16x16x32_bf16(a1, wk1[j], d, 0,0,0);
#pragma unroll
            for (int r = 0; r < 4; ++r)
                okb[qbase + (size_t)r * 64 + j * 16 + n16] = f2bf(d[r]);
        }
    }

    // Wv frags (reuse register space)
    bf16x8 wv0[4], wv1[4];
#pragma unroll
    for (int j = 0; j < 4; ++j) {
        const float* p = Wv + (j * 16 + n16) * 64 + quad * 8;
        wv0[j] = cvt8(p); wv1[j] = cvt8(p + 32);
    }
#pragma unroll
    for (int hh = 0; hh < 2; ++hh) {
        const int h = h0 + hh;
        const size_t aoff = (size_t)arow * DD + h * 64 + quad * 8;
        const size_t vbase = (size_t)orow * DD + h * 64;
        bf16x8 a0, a1;
        a0 = cvt8(values + aoff); a1 = cvt8(values + aoff + 32);
#pragma unroll
        for (int j = 0; j < 4; ++j) {
            f32x4 d = {0.f,0.f,0.f,0.f};
            d = __builtin_amdgcn_mfma_f32_16x16x32_bf16(a0, wv0[j], d, 0,0,0);
            d = __builtin_amdgcn_mfma_f32_16x16x32_bf16(a1, wv1[j], d, 0,0,0);
#pragma unroll
            for (int r = 0; r < 4; ++r)
                vb[vbase + (size_t)r * DD + j * 16 + n16] = f2bf(d[r]);
        }
        a0 = cvt8(ovals + aoff); a1 = cvt8(ovals + aoff + 32);
#pragma unroll
        for (int j = 0; j < 4; ++j) {
            f32x4 d = {0.f,0.f,0.f,0.f};
            d = __builtin_amdgcn_mfma_f32_16x16x32_bf16(a0, wv0[j], d, 0,0,0);
            d = __builtin_amdgcn_mfma_f32_16x16x32_bf16(a1, wv1[j], d, 0,0,0);
#pragma unroll
            for (int r = 0; r < 4; ++r)
                ovb[vbase + (size_t)r * DD + j * 16 + n16] = f2bf(d[r]);
        }
    }
}

// ---------------------------------------------------------------------------
// K2: per-row softmax denominator Z_q (and diag score) via MFMA.
// Block = (64-row q-tile, nh). Wave w holds Q frags for ALL 64 rows and
// processes k-16-tiles {w, w+4, ...} (strided split); block-reduce via LDS.
// ---------------------------------------------------------------------------
__global__ __launch_bounds__(256) void zrow_kernel(
    const unsigned short* __restrict__ qb, const unsigned short* __restrict__ okb,
    const float* __restrict__ ediag,
    float* __restrict__ invZ, float* __restrict__ diag_s)
{
    __shared__ float zs[4 * 64];
    const int qt = blockIdx.x;
    const int nh = blockIdx.y;
    const int t = threadIdx.x;
    const int w = t >> 6;
    const int lane = t & 63;
    const int n = lane & 15;
    const int quad = lane >> 4;
    const size_t base = (size_t)nh * (LL * 64);
    const size_t nhL = (size_t)nh * LL;

    bf16x8 aq[4][2];
#pragma unroll
    for (int rt = 0; rt < 4; ++rt) {
        const unsigned short* p = qb + base + (size_t)(qt*64 + rt*16 + n) * 64 + quad * 8;
        aq[rt][0] = ldfrag(p); aq[rt][1] = ldfrag(p + 32);
    }

    float zacc[4][4];
#pragma unroll
    for (int rt = 0; rt < 4; ++rt)
#pragma unroll
        for (int r = 0; r < 4; ++r) zacc[rt][r] = 0.f;

    for (int kt = w; kt < 4*qt + 4; kt += 4) {
        const unsigned short* kp = okb + base + (size_t)(kt*16 + n) * 64 + quad * 8;
        bf16x8 b0 = ldfrag(kp);
        bf16x8 b1 = ldfrag(kp + 32);
        const int dk = kt - 4*qt;   // <0: all row-tiles full
#pragma unroll
        for (int rt = 0; rt < 4; ++rt) {
            if (rt < dk) continue;                    // fully masked
            f32x4 d = {0.f,0.f,0.f,0.f};
            d = __builtin_amdgcn_mfma_f32_16x16x32_bf16(aq[rt][0], b0, d, 0,0,0);
            d = __builtin_amdgcn_mfma_f32_16x16x32_bf16(aq[rt][1], b1, d, 0,0,0);
            if (rt == dk) {                            // diagonal tile
#pragma unroll
                for (int r = 0; r < 4; ++r)
                    if (n < quad*4 + r) zacc[rt][r] += exp2f(d[r] * CEXP);
            } else {
#pragma unroll
                for (int r = 0; r < 4; ++r) zacc[rt][r] += exp2f(d[r] * CEXP);
            }
        }
    }

    // reduce over the 16 col lanes, deposit per-wave partials in LDS
#pragma unroll
    for (int rt = 0; rt < 4; ++rt)
#pragma unroll
        for (int r = 0; r < 4; ++r) {
            float z = zacc[rt][r];
            z += __shfl_xor(z, 1); z += __shfl_xor(z, 2);
            z += __shfl_xor(z, 4); z += __shfl_xor(z, 8);
            zacc[rt][r] = z;
        }
    if (n == 0) {
#pragma unroll
        for (int rt = 0; rt < 4; ++rt)
#pragma unroll
            for (int r = 0; r < 4; ++r)
                zs[w*64 + rt*16 + quad*4 + r] = zacc[rt][r];
    }
    __syncthreads();
    if (t < 64) {
        float z = zs[t] + zs[64 + t] + zs[128 + t] + zs[192 + t];
        const int gq = qt*64 + t;
        const float de = exp2f(ediag[nhL + gq] * CEXP);
        const float iz = 1.f / (z + de);
        invZ[nhL + gq]   = iz;
        diag_s[nhL + gq] = de * iz;
    }
}

// ---------------------------------------------------------------------------
// K3: colsum[l] = sum_{q>l} exp(e[q,l]/32) * invZ[q] via MFMA.
// Block = (64-col l-tile, nh). Wave w holds OK frags for ALL 64 cols and
// processes q-16-tiles {4lt+w, +4, ...}; block-reduce via LDS.
// ---------------------------------------------------------------------------
__global__ __launch_bounds__(256) void colsum_kernel(
    const unsigned short* __restrict__ qb, const unsigned short* __restrict__ okb,
    const float* __restrict__ invZ, float* __restrict__ colsum)
{
    __shared__ float cs[4 * 64];
    const int lt = blockIdx.x;
    const int nh = blockIdx.y;
    const int t = threadIdx.x;
    const int w = t >> 6;
    const int lane = t & 63;
    const int n = lane & 15;
    const int quad = lane >> 4;
    const size_t base = (size_t)nh * (LL * 64);
    const size_t nhL = (size_t)nh * LL;

    bf16x8 bl[4][2];
#pragma unroll
    for (int ct = 0; ct < 4; ++ct) {
        const unsigned short* p = okb + base + (size_t)(lt*64 + ct*16 + n) * 64 + quad * 8;
        bl[ct][0] = ldfrag(p); bl[ct][1] = ldfrag(p + 32);
    }

    float cacc[4] = {0.f, 0.f, 0.f, 0.f};

    for (int kt = 4*lt + w; kt < KT16; kt += 4) {
        const unsigned short* qp = qb + base + (size_t)(kt*16 + n) * 64 + quad * 8;
        bf16x8 a0 = ldfrag(qp);
        bf16x8 a1 = ldfrag(qp + 32);
        const float izq = invZ[nhL + kt*16 + n];
        float izr[4];
#pragma unroll
        for (int r = 0; r < 4; ++r) izr[r] = __shfl(izq, quad*4 + r);
        const int dk = kt - 4*lt;   // >=0 by construction
#pragma unroll
        for (int ct = 0; ct < 4; ++ct) {
            if (ct > dk) continue;                    // empty (q < l)
            f32x4 d = {0.f,0.f,0.f,0.f};
            d = __builtin_amdgcn_mfma_f32_16x16x32_bf16(a0, bl[ct][0], d, 0,0,0);
            d = __builtin_amdgcn_mfma_f32_16x16x32_bf16(a1, bl[ct][1], d, 0,0,0);
            if (ct == dk) {                            // diagonal tile: q>l only
#pragma unroll
                for (int r = 0; r < 4; ++r)
                    if (quad*4 + r > n) cacc[ct] += exp2f(d[r] * CEXP) * izr[r];
            } else {
#pragma unroll
                for (int r = 0; r < 4; ++r) cacc[ct] += exp2f(d[r] * CEXP) * izr[r];
            }
        }
    }

#pragma unroll
    for (int ct = 0; ct < 4; ++ct) {
        float c = cacc[ct];
        c += __shfl_down(c, 32);
        c += __shfl_down(c, 16);
        if (lane < 16) cs[w*64 + ct*16 + lane] = c;
    }
    __syncthreads();
    if (t < 64)
        colsum[nhL + lt*64 + t] = cs[t] + cs[64 + t] + cs[128 + t] + cs[192 + t];
}

// ---------------------------------------------------------------------------
// K4: fc_w -> bf16
// ---------------------------------------------------------------------------
__global__ __launch_bounds__(256) void fcw_kernel(
    const float* __restrict__ fc_w, unsigned short* __restrict__ fcwb)
{
    const int idx = blockIdx.x * 1024 + threadIdx.x * 4;
    float4 wv = *reinterpret_cast<const float4*>(fc_w + idx);
    ushort4 o;
    o.x = f2bf(wv.x); o.y = f2bf(wv.y); o.z = f2bf(wv.z); o.w = f2bf(wv.w);
    *reinterpret_cast<ushort4*>(fcwb + idx) = o;
}

// ---------------------------------------------------------------------------
// K5: attb[row][d] = bf16( diag_s*vb + colsum*ovb )
// ---------------------------------------------------------------------------
__global__ __launch_bounds__(256) void att_kernel(
    const unsigned short* __restrict__ vb, const unsigned short* __restrict__ ovb,
    const float* __restrict__ diag_s, const float* __restrict__ colsum,
    unsigned short* __restrict__ attb)
{
    const int row = blockIdx.x;            // n*L + l
    const int nn = row >> 11, l = row & 2047;
    const int t = threadIdx.x;
    const int d0 = t * 4;
    const int h = t >> 4;                  // d0>>6
    const size_t nhl = ((size_t)(nn * HH + h)) * LL + l;
    const float ds = diag_s[nhl];
    const float cs = colsum[nhl];
    const ushort4 v  = *reinterpret_cast<const ushort4*>(vb  + (size_t)row * DD + d0);
    const ushort4 ov = *reinterpret_cast<const ushort4*>(ovb + (size_t)row * DD + d0);
    ushort4 o;
    o.x = f2bf(ds * bf2f(v.x) + cs * bf2f(ov.x));
    o.y = f2bf(ds * bf2f(v.y) + cs * bf2f(ov.y));
    o.z = f2bf(ds * bf2f(v.z) + cs * bf2f(ov.z));
    o.w = f2bf(ds * bf2f(v.w) + cs * bf2f(ov.w));
    *reinterpret_cast<ushort4*>(attb + (size_t)row * DD + d0) = o;
}

// ---------------------------------------------------------------------------
// K6: out = attb @ fcwb^T + fc_b, bf16 MFMA GEMM. Block = 64x64 C tile.
// ---------------------------------------------------------------------------
__global__ __launch_bounds__(256) void out_kernel(
    const unsigned short* __restrict__ attb, const unsigned short* __restrict__ fcwb,
    const float* __restrict__ fc_b, float* __restrict__ out)
{
    const int nt = blockIdx.x;   // 0..15 col tile
    const int mt = blockIdx.y;   // 0..63 row tile
    const int t = threadIdx.x;
    const int w = t >> 6;
    const int lane = t & 63;
    const int n = lane & 15;
    const int quad = lane >> 4;

    f32x4 acc[4];
#pragma unroll
    for (int j = 0; j < 4; ++j) acc[j] = (f32x4){0.f, 0.f, 0.f, 0.f};

    const unsigned short* ap = attb + (size_t)(mt * 64 + w * 16 + n) * DD + quad * 8;
    const unsigned short* bp = fcwb + (size_t)(nt * 64 + n) * DD + quad * 8;

    for (int kc = 0; kc < DD; kc += 32) {
        bf16x8 a = ldfrag(ap + kc);
#pragma unroll
        for (int j = 0; j < 4; ++j) {
            bf16x8 b = ldfrag(bp + (size_t)(j * 16) * DD + kc);
            acc[j] = __builtin_amdgcn_mfma_f32_16x16x32_bf16(a, b, acc[j], 0, 0, 0);
        }
    }

#pragma unroll
    for (int j = 0; j < 4; ++j) {
        const int col = nt * 64 + j * 16 + n;
        const float bias = fc_b[col];
#pragma unroll
        for (int r = 0; r < 4; ++r) {
            const int grow = mt * 64 + w * 16 + quad * 4 + r;
            out[(size_t)grow * DD + col] = acc[j][r] + bias;
        }
    }
}

// ---------------------------------------------------------------------------
extern "C" void kernel_launch(void* const* d_in, const int* in_sizes, int n_in,
                              void* d_out, int out_size, void* d_ws, size_t ws_size,
                              hipStream_t stream) {
    const float* values = (const float*)d_in[0];
    const float* keys   = (const float*)d_in[1];
    const float* query  = (const float*)d_in[2];
    const float* ovals  = (const float*)d_in[3];
    const float* okeys  = (const float*)d_in[4];
    const float* Wv     = (const float*)d_in[5];
    const float* Wk     = (const float*)d_in[6];
    const float* Wq     = (const float*)d_in[7];
    const float* fc_w   = (const float*)d_in[8];
    const float* fc_b   = (const float*)d_in[9];
    // d_in[10]: mask — HIST==L makes it pure causal, handled analytically.
    float* out = (float*)d_out;

    float* ws      = (float*)d_ws;
    float* ediag   = ws;                     // 65536 f32
    float* invZ    = ediag + 65536;
    float* diag_s  = invZ + 65536;
    float* colsum  = diag_s + 65536;
    unsigned short* qb   = (unsigned short*)(colsum + 65536);  // [32][2048][64] bf16
    unsigned short* okb  = qb   + 4194304;
    unsigned short* vb   = okb  + 4194304;   // [n][l][1024] bf16
    unsigned short* ovb  = vb   + 4194304;
    unsigned short* attb = ovb  + 4194304;   // [4096][1024] bf16
    unsigned short* fcwb = attb + 4194304;   // [1024][1024] bf16
    // total ~= 1 MB + 11 * 8.4 MB/2 ... ~= 46 MB

    proj_kernel<<<dim3(64, 8), 256, 0, stream>>>(
        values, keys, query, ovals, okeys, Wv, Wk, Wq, qb, okb, vb, ovb, ediag);
    fcw_kernel<<<dim3(1024), 256, 0, stream>>>(fc_w, fcwb);
    zrow_kernel<<<dim3(LT, NHH), 256, 0, stream>>>(qb, okb, ediag, invZ, diag_s);
    colsum_kernel<<<dim3(LT, NHH), 256, 0, stream>>>(qb, okb, invZ, colsum);
    att_kernel<<<dim3(NB * LL), 256, 0, stream>>>(vb, ovb, diag_s, colsum, attb);
    out_kernel<<<dim3(16, 64), 256, 0, stream>>>(attb, fcwb, fc_b, out);
}

// Round 4
// 316.138 us; speedup vs baseline: 4.3566x; 1.0736x over previous
//
#include <hip/hip_runtime.h>

// Problem constants
#define NB 2
#define LL 2048
#define DD 1024
#define HH 16
#define NHH (NB*HH)          // 32 (n,h) pairs
#define LT (LL/64)           // 32 tiles of 64
#define KT16 (LL/16)         // 128 16-col tiles
#define CEXP 0.0450842200277801f   // log2(e)/32 : exp(x/32) == exp2(x*CEXP)

typedef __bf16 bf16x8 __attribute__((ext_vector_type(8)));
typedef unsigned short u16x8 __attribute__((ext_vector_type(8)));
typedef float f32x4 __attribute__((ext_vector_type(4)));

__device__ __forceinline__ unsigned short f2bf(float f) {
    unsigned u = __float_as_uint(f);
    return (unsigned short)((u + 0x7fffu + ((u >> 16) & 1u)) >> 16);   // RNE
}
__device__ __forceinline__ float bf2f(unsigned short u) {
    return __uint_as_float(((unsigned)u) << 16);
}
__device__ __forceinline__ bf16x8 ldfrag(const unsigned short* p) {
    return *reinterpret_cast<const bf16x8*>(p);
}
// 8 consecutive fp32 -> bf16x8 fragment
__device__ __forceinline__ bf16x8 cvt8(const float* p) {
    float4 a = *reinterpret_cast<const float4*>(p);
    float4 b = *reinterpret_cast<const float4*>(p + 4);
    u16x8 u;
    u[0]=f2bf(a.x); u[1]=f2bf(a.y); u[2]=f2bf(a.z); u[3]=f2bf(a.w);
    u[4]=f2bf(b.x); u[5]=f2bf(b.y); u[6]=f2bf(b.z); u[7]=f2bf(b.w);
    return __builtin_bit_cast(bf16x8, u);
}

// ---------------------------------------------------------------------------
// K1: projections via MFMA. Block = 64 rows x 2 heads; 4 waves, wave w owns
// rows rb+w*16..+15 for both heads, all 5 inputs. W (64x64, head-shared)
// held as 8 B-frags per matrix in VGPRs. ediag from q/k C-frags.
// ---------------------------------------------------------------------------
__global__ __launch_bounds__(256) void proj_kernel(
    const float* __restrict__ values, const float* __restrict__ keys,
    const float* __restrict__ query,  const float* __restrict__ ovals,
    const float* __restrict__ okeys,  const float* __restrict__ Wv,
    const float* __restrict__ Wk,     const float* __restrict__ Wq,
    unsigned short* __restrict__ qb, unsigned short* __restrict__ okb,
    unsigned short* __restrict__ vb, unsigned short* __restrict__ ovb,
    float* __restrict__ ediag)
{
    const int rb = blockIdx.x * 64;     // row base in (n*L+l) space
    const int h0 = blockIdx.y * 2;      // first of 2 heads
    const int t = threadIdx.x;
    const int w = t >> 6;
    const int lane = t & 63;
    const int n16 = lane & 15;
    const int quad = lane >> 4;
    const int arow = rb + w * 16 + n16;       // A-frag source row
    const int orow = rb + w * 16 + quad * 4;  // C-frag row base (+r)
    const int onb = orow >> 11;
    const int olb = orow & 2047;

    // B frags: W[j*16+n16][quad*8 ...]
    bf16x8 wk0[4], wk1[4], wq0[4], wq1[4];
#pragma unroll
    for (int j = 0; j < 4; ++j) {
        const float* p = Wk + (j * 16 + n16) * 64 + quad * 8;
        wk0[j] = cvt8(p); wk1[j] = cvt8(p + 32);
        const float* q = Wq + (j * 16 + n16) * 64 + quad * 8;
        wq0[j] = cvt8(q); wq1[j] = cvt8(q + 32);
    }

#pragma unroll
    for (int hh = 0; hh < 2; ++hh) {
        const int h = h0 + hh;
        const size_t aoff = (size_t)arow * DD + h * 64 + quad * 8;
        bf16x8 a0, a1;
        f32x4 ka[4], qa[4];

        a0 = cvt8(keys + aoff); a1 = cvt8(keys + aoff + 32);
#pragma unroll
        for (int j = 0; j < 4; ++j) {
            f32x4 d = {0.f,0.f,0.f,0.f};
            d = __builtin_amdgcn_mfma_f32_16x16x32_bf16(a0, wk0[j], d, 0,0,0);
            ka[j] = __builtin_amdgcn_mfma_f32_16x16x32_bf16(a1, wk1[j], d, 0,0,0);
        }
        a0 = cvt8(query + aoff); a1 = cvt8(query + aoff + 32);
#pragma unroll
        for (int j = 0; j < 4; ++j) {
            f32x4 d = {0.f,0.f,0.f,0.f};
            d = __builtin_amdgcn_mfma_f32_16x16x32_bf16(a0, wq0[j], d, 0,0,0);
            qa[j] = __builtin_amdgcn_mfma_f32_16x16x32_bf16(a1, wq1[j], d, 0,0,0);
        }
        // store q projection
        const size_t qbase = (((size_t)(onb * HH + h)) * LL + olb) * 64;
#pragma unroll
        for (int j = 0; j < 4; ++j)
#pragma unroll
            for (int r = 0; r < 4; ++r)
                qb[qbase + (size_t)r * 64 + j * 16 + n16] = f2bf(qa[j][r]);
        // ediag = rowwise dot(q,k): sum over j then over the 16 n-lanes
#pragma unroll
        for (int r = 0; r < 4; ++r) {
            float p = qa[0][r]*ka[0][r] + qa[1][r]*ka[1][r]
                    + qa[2][r]*ka[2][r] + qa[3][r]*ka[3][r];
            p += __shfl_xor(p, 1); p += __shfl_xor(p, 2);
            p += __shfl_xor(p, 4); p += __shfl_xor(p, 8);
            if (n16 == 0)
                ediag[((size_t)(onb * HH + h)) * LL + olb + r] = p;
        }
        // origin_keys projection (uses Wk)
        a0 = cvt8(okeys + aoff); a1 = cvt8(okeys + aoff + 32);
#pragma unroll
        for (int j = 0; j < 4; ++j) {
            f32x4 d = {0.f,0.f,0.f,0.f};
            d = __builtin_amdgcn_mfma_f32_16x16x32_bf16(a0, wk0[j], d, 0,0,0);
            d = __builtin_amdgcn_mfma_f32_16x16x32_bf16(a1, wk1[j], d, 0,0,0);
#pragma unroll
            for (int r = 0; r < 4; ++r)
                okb[qbase + (size_t)r * 64 + j * 16 + n16] = f2bf(d[r]);
        }
    }

    // Wv frags (reuse register space)
    bf16x8 wv0[4], wv1[4];
#pragma unroll
    for (int j = 0; j < 4; ++j) {
        const float* p = Wv + (j * 16 + n16) * 64 + quad * 8;
        wv0[j] = cvt8(p); wv1[j] = cvt8(p + 32);
    }
#pragma unroll
    for (int hh = 0; hh < 2; ++hh) {
        const int h = h0 + hh;
        const size_t aoff = (size_t)arow * DD + h * 64 + quad * 8;
        const size_t vbase = (size_t)orow * DD + h * 64;
        bf16x8 a0, a1;
        a0 = cvt8(values + aoff); a1 = cvt8(values + aoff + 32);
#pragma unroll
        for (int j = 0; j < 4; ++j) {
            f32x4 d = {0.f,0.f,0.f,0.f};
            d = __builtin_amdgcn_mfma_f32_16x16x32_bf16(a0, wv0[j], d, 0,0,0);
            d = __builtin_amdgcn_mfma_f32_16x16x32_bf16(a1, wv1[j], d, 0,0,0);
#pragma unroll
            for (int r = 0; r < 4; ++r)
                vb[vbase + (size_t)r * DD + j * 16 + n16] = f2bf(d[r]);
        }
        a0 = cvt8(ovals + aoff); a1 = cvt8(ovals + aoff + 32);
#pragma unroll
        for (int j = 0; j < 4; ++j) {
            f32x4 d = {0.f,0.f,0.f,0.f};
            d = __builtin_amdgcn_mfma_f32_16x16x32_bf16(a0, wv0[j], d, 0,0,0);
            d = __builtin_amdgcn_mfma_f32_16x16x32_bf16(a1, wv1[j], d, 0,0,0);
#pragma unroll
            for (int r = 0; r < 4; ++r)
                ovb[vbase + (size_t)r * DD + j * 16 + n16] = f2bf(d[r]);
        }
    }
}

// ---------------------------------------------------------------------------
// K2: per-row softmax denominator Z_q (and diag score) via MFMA.
// Block = (64-row q-tile, nh). Wave w holds Q frags for ALL 64 rows and
// processes k-16-tiles {w, w+4, ...} (strided split); block-reduce via LDS.
// ---------------------------------------------------------------------------
__global__ __launch_bounds__(256) void zrow_kernel(
    const unsigned short* __restrict__ qb, const unsigned short* __restrict__ okb,
    const float* __restrict__ ediag,
    float* __restrict__ invZ, float* __restrict__ diag_s)
{
    __shared__ float zs[4 * 64];
    const int qt = blockIdx.x;
    const int nh = blockIdx.y;
    const int t = threadIdx.x;
    const int w = t >> 6;
    const int lane = t & 63;
    const int n = lane & 15;
    const int quad = lane >> 4;
    const size_t base = (size_t)nh * (LL * 64);
    const size_t nhL = (size_t)nh * LL;

    bf16x8 aq[4][2];
#pragma unroll
    for (int rt = 0; rt < 4; ++rt) {
        const unsigned short* p = qb + base + (size_t)(qt*64 + rt*16 + n) * 64 + quad * 8;
        aq[rt][0] = ldfrag(p); aq[rt][1] = ldfrag(p + 32);
    }

    float zacc[4][4];
#pragma unroll
    for (int rt = 0; rt < 4; ++rt)
#pragma unroll
        for (int r = 0; r < 4; ++r) zacc[rt][r] = 0.f;

    for (int kt = w; kt < 4*qt + 4; kt += 4) {
        const unsigned short* kp = okb + base + (size_t)(kt*16 + n) * 64 + quad * 8;
        bf16x8 b0 = ldfrag(kp);
        bf16x8 b1 = ldfrag(kp + 32);
        const int dk = kt - 4*qt;   // <0: all row-tiles full
#pragma unroll
        for (int rt = 0; rt < 4; ++rt) {
            if (rt < dk) continue;                    // fully masked
            f32x4 d = {0.f,0.f,0.f,0.f};
            d = __builtin_amdgcn_mfma_f32_16x16x32_bf16(aq[rt][0], b0, d, 0,0,0);
            d = __builtin_amdgcn_mfma_f32_16x16x32_bf16(aq[rt][1], b1, d, 0,0,0);
            if (rt == dk) {                            // diagonal tile
#pragma unroll
                for (int r = 0; r < 4; ++r)
                    if (n < quad*4 + r) zacc[rt][r] += exp2f(d[r] * CEXP);
            } else {
#pragma unroll
                for (int r = 0; r < 4; ++r) zacc[rt][r] += exp2f(d[r] * CEXP);
            }
        }
    }

    // reduce over the 16 col lanes, deposit per-wave partials in LDS
#pragma unroll
    for (int rt = 0; rt < 4; ++rt)
#pragma unroll
        for (int r = 0; r < 4; ++r) {
            float z = zacc[rt][r];
            z += __shfl_xor(z, 1); z += __shfl_xor(z, 2);
            z += __shfl_xor(z, 4); z += __shfl_xor(z, 8);
            zacc[rt][r] = z;
        }
    if (n == 0) {
#pragma unroll
        for (int rt = 0; rt < 4; ++rt)
#pragma unroll
            for (int r = 0; r < 4; ++r)
                zs[w*64 + rt*16 + quad*4 + r] = zacc[rt][r];
    }
    __syncthreads();
    if (t < 64) {
        float z = zs[t] + zs[64 + t] + zs[128 + t] + zs[192 + t];
        const int gq = qt*64 + t;
        const float de = exp2f(ediag[nhL + gq] * CEXP);
        const float iz = 1.f / (z + de);
        invZ[nhL + gq]   = iz;
        diag_s[nhL + gq] = de * iz;
    }
}

// ---------------------------------------------------------------------------
// K3: colsum[l] = sum_{q>l} exp(e[q,l]/32) * invZ[q] via MFMA.
// Block = (64-col l-tile, nh). Wave w holds OK frags for ALL 64 cols and
// processes q-16-tiles {4lt+w, +4, ...}; block-reduce via LDS.
// ---------------------------------------------------------------------------
__global__ __launch_bounds__(256) void colsum_kernel(
    const unsigned short* __restrict__ qb, const unsigned short* __restrict__ okb,
    const float* __restrict__ invZ, float* __restrict__ colsum)
{
    __shared__ float cs[4 * 64];
    const int lt = blockIdx.x;
    const int nh = blockIdx.y;
    const int t = threadIdx.x;
    const int w = t >> 6;
    const int lane = t & 63;
    const int n = lane & 15;
    const int quad = lane >> 4;
    const size_t base = (size_t)nh * (LL * 64);
    const size_t nhL = (size_t)nh * LL;

    bf16x8 bl[4][2];
#pragma unroll
    for (int ct = 0; ct < 4; ++ct) {
        const unsigned short* p = okb + base + (size_t)(lt*64 + ct*16 + n) * 64 + quad * 8;
        bl[ct][0] = ldfrag(p); bl[ct][1] = ldfrag(p + 32);
    }

    float cacc[4] = {0.f, 0.f, 0.f, 0.f};

    for (int kt = 4*lt + w; kt < KT16; kt += 4) {
        const unsigned short* qp = qb + base + (size_t)(kt*16 + n) * 64 + quad * 8;
        bf16x8 a0 = ldfrag(qp);
        bf16x8 a1 = ldfrag(qp + 32);
        const float izq = invZ[nhL + kt*16 + n];
        float izr[4];
#pragma unroll
        for (int r = 0; r < 4; ++r) izr[r] = __shfl(izq, quad*4 + r);
        const int dk = kt - 4*lt;   // >=0 by construction
#pragma unroll
        for (int ct = 0; ct < 4; ++ct) {
            if (ct > dk) continue;                    // empty (q < l)
            f32x4 d = {0.f,0.f,0.f,0.f};
            d = __builtin_amdgcn_mfma_f32_16x16x32_bf16(a0, bl[ct][0], d, 0,0,0);
            d = __builtin_amdgcn_mfma_f32_16x16x32_bf16(a1, bl[ct][1], d, 0,0,0);
            if (ct == dk) {                            // diagonal tile: q>l only
#pragma unroll
                for (int r = 0; r < 4; ++r)
                    if (quad*4 + r > n) cacc[ct] += exp2f(d[r] * CEXP) * izr[r];
            } else {
#pragma unroll
                for (int r = 0; r < 4; ++r) cacc[ct] += exp2f(d[r] * CEXP) * izr[r];
            }
        }
    }

#pragma unroll
    for (int ct = 0; ct < 4; ++ct) {
        float c = cacc[ct];
        c += __shfl_down(c, 32);
        c += __shfl_down(c, 16);
        if (lane < 16) cs[w*64 + ct*16 + lane] = c;
    }
    __syncthreads();
    if (t < 64)
        colsum[nhL + lt*64 + t] = cs[t] + cs[64 + t] + cs[128 + t] + cs[192 + t];
}

// ---------------------------------------------------------------------------
// K4: fc_w -> bf16
// ---------------------------------------------------------------------------
__global__ __launch_bounds__(256) void fcw_kernel(
    const float* __restrict__ fc_w, unsigned short* __restrict__ fcwb)
{
    const int idx = blockIdx.x * 1024 + threadIdx.x * 4;
    float4 wv = *reinterpret_cast<const float4*>(fc_w + idx);
    ushort4 o;
    o.x = f2bf(wv.x); o.y = f2bf(wv.y); o.z = f2bf(wv.z); o.w = f2bf(wv.w);
    *reinterpret_cast<ushort4*>(fcwb + idx) = o;
}

// ---------------------------------------------------------------------------
// K5: attb[row][d] = bf16( diag_s*vb + colsum*ovb )
// ---------------------------------------------------------------------------
__global__ __launch_bounds__(256) void att_kernel(
    const unsigned short* __restrict__ vb, const unsigned short* __restrict__ ovb,
    const float* __restrict__ diag_s, const float* __restrict__ colsum,
    unsigned short* __restrict__ attb)
{
    const int row = blockIdx.x;            // n*L + l
    const int nn = row >> 11, l = row & 2047;
    const int t = threadIdx.x;
    const int d0 = t * 4;
    const int h = t >> 4;                  // d0>>6
    const size_t nhl = ((size_t)(nn * HH + h)) * LL + l;
    const float ds = diag_s[nhl];
    const float cs = colsum[nhl];
    const ushort4 v  = *reinterpret_cast<const ushort4*>(vb  + (size_t)row * DD + d0);
    const ushort4 ov = *reinterpret_cast<const ushort4*>(ovb + (size_t)row * DD + d0);
    ushort4 o;
    o.x = f2bf(ds * bf2f(v.x) + cs * bf2f(ov.x));
    o.y = f2bf(ds * bf2f(v.y) + cs * bf2f(ov.y));
    o.z = f2bf(ds * bf2f(v.z) + cs * bf2f(ov.z));
    o.w = f2bf(ds * bf2f(v.w) + cs * bf2f(ov.w));
    *reinterpret_cast<ushort4*>(attb + (size_t)row * DD + d0) = o;
}

// ---------------------------------------------------------------------------
// K6: out = attb @ fcwb^T + fc_b, bf16 MFMA GEMM, register-pipelined.
// Grid (16 col-tiles [fast], 32 row-tiles). Block = 4 waves; wave w owns a
// 32x64 C tile (2 m-frags x 4 n-frags = 8 MFMAs per 32-k step, 6 frag loads).
// Double-buffered register prefetch hides L2 latency; consecutive blockIdx.x
// share the A slab and cycle the whole 2 MB B through L2.
// ---------------------------------------------------------------------------
__global__ __launch_bounds__(256) void out_kernel(
    const unsigned short* __restrict__ attb, const unsigned short* __restrict__ fcwb,
    const float* __restrict__ fc_b, float* __restrict__ out)
{
    const int ct = blockIdx.x;   // 0..15  col tile (64 cols)
    const int rt = blockIdx.y;   // 0..31  row tile (128 rows)
    const int t = threadIdx.x;
    const int w = t >> 6;
    const int lane = t & 63;
    const int n = lane & 15;
    const int quad = lane >> 4;

    const int row0 = rt * 128 + w * 32;
    const int col0 = ct * 64;

    const unsigned short* ap = attb + (size_t)(row0 + n) * DD + quad * 8;
    const unsigned short* bp = fcwb + (size_t)(col0 + n) * DD + quad * 8;

    f32x4 acc[2][4];
#pragma unroll
    for (int i = 0; i < 2; ++i)
#pragma unroll
        for (int j = 0; j < 4; ++j) acc[i][j] = (f32x4){0.f, 0.f, 0.f, 0.f};

    bf16x8 a[2][2], b[2][4];
    a[0][0] = ldfrag(ap);
    a[0][1] = ldfrag(ap + 16 * DD);
#pragma unroll
    for (int j = 0; j < 4; ++j) b[0][j] = ldfrag(bp + (size_t)(j * 16) * DD);

    int cur = 0;
    for (int kc = 0; kc < DD; kc += 32) {
        const int nxt = cur ^ 1;
        if (kc + 32 < DD) {
            a[nxt][0] = ldfrag(ap + kc + 32);
            a[nxt][1] = ldfrag(ap + 16 * DD + kc + 32);
#pragma unroll
            for (int j = 0; j < 4; ++j)
                b[nxt][j] = ldfrag(bp + (size_t)(j * 16) * DD + kc + 32);
        }
#pragma unroll
        for (int i = 0; i < 2; ++i)
#pragma unroll
            for (int j = 0; j < 4; ++j)
                acc[i][j] = __builtin_amdgcn_mfma_f32_16x16x32_bf16(
                    a[cur][i], b[cur][j], acc[i][j], 0, 0, 0);
        cur = nxt;
    }

#pragma unroll
    for (int j = 0; j < 4; ++j) {
        const int col = col0 + j * 16 + n;
        const float bias = fc_b[col];
#pragma unroll
        for (int i = 0; i < 2; ++i)
#pragma unroll
            for (int r = 0; r < 4; ++r) {
                const int grow = row0 + i * 16 + quad * 4 + r;
                out[(size_t)grow * DD + col] = acc[i][j][r] + bias;
            }
    }
}

// ---------------------------------------------------------------------------
extern "C" void kernel_launch(void* const* d_in, const int* in_sizes, int n_in,
                              void* d_out, int out_size, void* d_ws, size_t ws_size,
                              hipStream_t stream) {
    const float* values = (const float*)d_in[0];
    const float* keys   = (const float*)d_in[1];
    const float* query  = (const float*)d_in[2];
    const float* ovals  = (const float*)d_in[3];
    const float* okeys  = (const float*)d_in[4];
    const float* Wv     = (const float*)d_in[5];
    const float* Wk     = (const float*)d_in[6];
    const float* Wq     = (const float*)d_in[7];
    const float* fc_w   = (const float*)d_in[8];
    const float* fc_b   = (const float*)d_in[9];
    // d_in[10]: mask — HIST==L makes it pure causal, handled analytically.
    float* out = (float*)d_out;

    float* ws      = (float*)d_ws;
    float* ediag   = ws;                     // 65536 f32
    float* invZ    = ediag + 65536;
    float* diag_s  = invZ + 65536;
    float* colsum  = diag_s + 65536;
    unsigned short* qb   = (unsigned short*)(colsum + 65536);  // [32][2048][64] bf16
    unsigned short* okb  = qb   + 4194304;
    unsigned short* vb   = okb  + 4194304;   // [n][l][1024] bf16
    unsigned short* ovb  = vb   + 4194304;
    unsigned short* attb = ovb  + 4194304;   // [4096][1024] bf16
    unsigned short* fcwb = attb + 4194304;   // [1024][1024] bf16

    proj_kernel<<<dim3(64, 8), 256, 0, stream>>>(
        values, keys, query, ovals, okeys, Wv, Wk, Wq, qb, okb, vb, ovb, ediag);
    fcw_kernel<<<dim3(1024), 256, 0, stream>>>(fc_w, fcwb);
    zrow_kernel<<<dim3(LT, NHH), 256, 0, stream>>>(qb, okb, ediag, invZ, diag_s);
    colsum_kernel<<<dim3(LT, NHH), 256, 0, stream>>>(qb, okb, invZ, colsum);
    att_kernel<<<dim3(NB * LL), 256, 0, stream>>>(vb, ovb, diag_s, colsum, attb);
    out_kernel<<<dim3(16, 32), 256, 0, stream>>>(attb, fcwb, fc_b, out);
}

// Round 5
// 299.422 us; speedup vs baseline: 4.5998x; 1.0558x over previous
//
#include <hip/hip_runtime.h>

// Problem constants
#define NB 2
#define LL 2048
#define DD 1024
#define HH 16
#define NHH (NB*HH)          // 32 (n,h) pairs
#define LT (LL/64)           // 32 tiles of 64
#define KT16 (LL/16)         // 128 16-col tiles
#define CEXP 0.0450842200277801f   // log2(e)/32 : exp(x/32) == exp2(x*CEXP)

typedef __bf16 bf16x8 __attribute__((ext_vector_type(8)));
typedef unsigned short u16x8 __attribute__((ext_vector_type(8)));
typedef float f32x4 __attribute__((ext_vector_type(4)));

__device__ __forceinline__ unsigned short f2bf(float f) {
    unsigned u = __float_as_uint(f);
    return (unsigned short)((u + 0x7fffu + ((u >> 16) & 1u)) >> 16);   // RNE
}
__device__ __forceinline__ float bf2f(unsigned short u) {
    return __uint_as_float(((unsigned)u) << 16);
}
__device__ __forceinline__ bf16x8 ldfrag(const unsigned short* p) {
    return *reinterpret_cast<const bf16x8*>(p);
}
// 8 consecutive fp32 -> bf16x8 fragment
__device__ __forceinline__ bf16x8 cvt8(const float* p) {
    float4 a = *reinterpret_cast<const float4*>(p);
    float4 b = *reinterpret_cast<const float4*>(p + 4);
    u16x8 u;
    u[0]=f2bf(a.x); u[1]=f2bf(a.y); u[2]=f2bf(a.z); u[3]=f2bf(a.w);
    u[4]=f2bf(b.x); u[5]=f2bf(b.y); u[6]=f2bf(b.z); u[7]=f2bf(b.w);
    return __builtin_bit_cast(bf16x8, u);
}

// ---------------------------------------------------------------------------
// K1: projections via MFMA. Block = 64 rows x 2 heads; 4 waves, wave w owns
// rows rb+w*16..+15 for both heads, all 5 inputs. W (64x64, head-shared)
// held as 8 B-frags per matrix in VGPRs. ediag from q/k C-frags.
// ---------------------------------------------------------------------------
__global__ __launch_bounds__(256) void proj_kernel(
    const float* __restrict__ values, const float* __restrict__ keys,
    const float* __restrict__ query,  const float* __restrict__ ovals,
    const float* __restrict__ okeys,  const float* __restrict__ Wv,
    const float* __restrict__ Wk,     const float* __restrict__ Wq,
    unsigned short* __restrict__ qb, unsigned short* __restrict__ okb,
    unsigned short* __restrict__ vb, unsigned short* __restrict__ ovb,
    float* __restrict__ ediag)
{
    const int rb = blockIdx.x * 64;     // row base in (n*L+l) space
    const int h0 = blockIdx.y * 2;      // first of 2 heads
    const int t = threadIdx.x;
    const int w = t >> 6;
    const int lane = t & 63;
    const int n16 = lane & 15;
    const int quad = lane >> 4;
    const int arow = rb + w * 16 + n16;       // A-frag source row
    const int orow = rb + w * 16 + quad * 4;  // C-frag row base (+r)
    const int onb = orow >> 11;
    const int olb = orow & 2047;

    // B frags: W[j*16+n16][quad*8 ...]
    bf16x8 wk0[4], wk1[4], wq0[4], wq1[4];
#pragma unroll
    for (int j = 0; j < 4; ++j) {
        const float* p = Wk + (j * 16 + n16) * 64 + quad * 8;
        wk0[j] = cvt8(p); wk1[j] = cvt8(p + 32);
        const float* q = Wq + (j * 16 + n16) * 64 + quad * 8;
        wq0[j] = cvt8(q); wq1[j] = cvt8(q + 32);
    }

#pragma unroll
    for (int hh = 0; hh < 2; ++hh) {
        const int h = h0 + hh;
        const size_t aoff = (size_t)arow * DD + h * 64 + quad * 8;
        bf16x8 a0, a1;
        f32x4 ka[4], qa[4];

        a0 = cvt8(keys + aoff); a1 = cvt8(keys + aoff + 32);
#pragma unroll
        for (int j = 0; j < 4; ++j) {
            f32x4 d = {0.f,0.f,0.f,0.f};
            d = __builtin_amdgcn_mfma_f32_16x16x32_bf16(a0, wk0[j], d, 0,0,0);
            ka[j] = __builtin_amdgcn_mfma_f32_16x16x32_bf16(a1, wk1[j], d, 0,0,0);
        }
        a0 = cvt8(query + aoff); a1 = cvt8(query + aoff + 32);
#pragma unroll
        for (int j = 0; j < 4; ++j) {
            f32x4 d = {0.f,0.f,0.f,0.f};
            d = __builtin_amdgcn_mfma_f32_16x16x32_bf16(a0, wq0[j], d, 0,0,0);
            qa[j] = __builtin_amdgcn_mfma_f32_16x16x32_bf16(a1, wq1[j], d, 0,0,0);
        }
        // store q projection
        const size_t qbase = (((size_t)(onb * HH + h)) * LL + olb) * 64;
#pragma unroll
        for (int j = 0; j < 4; ++j)
#pragma unroll
            for (int r = 0; r < 4; ++r)
                qb[qbase + (size_t)r * 64 + j * 16 + n16] = f2bf(qa[j][r]);
        // ediag = rowwise dot(q,k): sum over j then over the 16 n-lanes
#pragma unroll
        for (int r = 0; r < 4; ++r) {
            float p = qa[0][r]*ka[0][r] + qa[1][r]*ka[1][r]
                    + qa[2][r]*ka[2][r] + qa[3][r]*ka[3][r];
            p += __shfl_xor(p, 1); p += __shfl_xor(p, 2);
            p += __shfl_xor(p, 4); p += __shfl_xor(p, 8);
            if (n16 == 0)
                ediag[((size_t)(onb * HH + h)) * LL + olb + r] = p;
        }
        // origin_keys projection (uses Wk)
        a0 = cvt8(okeys + aoff); a1 = cvt8(okeys + aoff + 32);
#pragma unroll
        for (int j = 0; j < 4; ++j) {
            f32x4 d = {0.f,0.f,0.f,0.f};
            d = __builtin_amdgcn_mfma_f32_16x16x32_bf16(a0, wk0[j], d, 0,0,0);
            d = __builtin_amdgcn_mfma_f32_16x16x32_bf16(a1, wk1[j], d, 0,0,0);
#pragma unroll
            for (int r = 0; r < 4; ++r)
                okb[qbase + (size_t)r * 64 + j * 16 + n16] = f2bf(d[r]);
        }
    }

    // Wv frags (reuse register space)
    bf16x8 wv0[4], wv1[4];
#pragma unroll
    for (int j = 0; j < 4; ++j) {
        const float* p = Wv + (j * 16 + n16) * 64 + quad * 8;
        wv0[j] = cvt8(p); wv1[j] = cvt8(p + 32);
    }
#pragma unroll
    for (int hh = 0; hh < 2; ++hh) {
        const int h = h0 + hh;
        const size_t aoff = (size_t)arow * DD + h * 64 + quad * 8;
        const size_t vbase = (size_t)orow * DD + h * 64;
        bf16x8 a0, a1;
        a0 = cvt8(values + aoff); a1 = cvt8(values + aoff + 32);
#pragma unroll
        for (int j = 0; j < 4; ++j) {
            f32x4 d = {0.f,0.f,0.f,0.f};
            d = __builtin_amdgcn_mfma_f32_16x16x32_bf16(a0, wv0[j], d, 0,0,0);
            d = __builtin_amdgcn_mfma_f32_16x16x32_bf16(a1, wv1[j], d, 0,0,0);
#pragma unroll
            for (int r = 0; r < 4; ++r)
                vb[vbase + (size_t)r * DD + j * 16 + n16] = f2bf(d[r]);
        }
        a0 = cvt8(ovals + aoff); a1 = cvt8(ovals + aoff + 32);
#pragma unroll
        for (int j = 0; j < 4; ++j) {
            f32x4 d = {0.f,0.f,0.f,0.f};
            d = __builtin_amdgcn_mfma_f32_16x16x32_bf16(a0, wv0[j], d, 0,0,0);
            d = __builtin_amdgcn_mfma_f32_16x16x32_bf16(a1, wv1[j], d, 0,0,0);
#pragma unroll
            for (int r = 0; r < 4; ++r)
                ovb[vbase + (size_t)r * DD + j * 16 + n16] = f2bf(d[r]);
        }
    }
}

// ---------------------------------------------------------------------------
// K2: partial row-sums of exp(E/32) via MFMA, load-balanced.
// Block (px, nh): pair p = px>>2 handles q-tiles {p, 31-p} (combined work is
// constant); residue class s = px&3 with wave w takes k-16-tiles
// kt ≡ 4s+w (mod 16). Partials accumulate to Zbuf via global fp32 atomics.
// Register-dbuf prefetch of B frags; no LDS, no __syncthreads.
// ---------------------------------------------------------------------------
__global__ __launch_bounds__(256) void zrow_part(
    const unsigned short* __restrict__ qb, const unsigned short* __restrict__ okb,
    float* __restrict__ Zbuf)
{
    const int px = blockIdx.x;
    const int pair = px >> 2;
    const int s = px & 3;
    const int nh = blockIdx.y;
    const int t = threadIdx.x;
    const int w = t >> 6;
    const int lane = t & 63;
    const int n = lane & 15;
    const int quad = lane >> 4;
    const size_t base = (size_t)nh * (LL * 64);
    const size_t nhL = (size_t)nh * LL;
    const int r0 = 4 * s + w;     // k-tile residue 0..15

#pragma unroll
    for (int half = 0; half < 2; ++half) {
        const int qt = half ? (31 - pair) : pair;
        const int kend = 4 * qt + 4;

        bf16x8 aq[4][2];
#pragma unroll
        for (int rt = 0; rt < 4; ++rt) {
            const unsigned short* p = qb + base + (size_t)(qt*64 + rt*16 + n) * 64 + quad * 8;
            aq[rt][0] = ldfrag(p); aq[rt][1] = ldfrag(p + 32);
        }

        float zacc[4][4];
#pragma unroll
        for (int rt = 0; rt < 4; ++rt)
#pragma unroll
            for (int r = 0; r < 4; ++r) zacc[rt][r] = 0.f;

        bf16x8 b0c, b1c;
        if (r0 < kend) {
            const unsigned short* kp = okb + base + (size_t)(r0*16 + n) * 64 + quad * 8;
            b0c = ldfrag(kp); b1c = ldfrag(kp + 32);
        }
        for (int kt = r0; kt < kend; kt += 16) {
            bf16x8 b0 = b0c, b1 = b1c;
            if (kt + 16 < kend) {
                const unsigned short* kp = okb + base + (size_t)((kt+16)*16 + n) * 64 + quad * 8;
                b0c = ldfrag(kp); b1c = ldfrag(kp + 32);
            }
            const int dk = kt - 4*qt;   // <0: all row-tiles full
#pragma unroll
            for (int rt = 0; rt < 4; ++rt) {
                if (rt < dk) continue;                    // fully masked
                f32x4 d = {0.f,0.f,0.f,0.f};
                d = __builtin_amdgcn_mfma_f32_16x16x32_bf16(aq[rt][0], b0, d, 0,0,0);
                d = __builtin_amdgcn_mfma_f32_16x16x32_bf16(aq[rt][1], b1, d, 0,0,0);
                if (rt == dk) {                            // diagonal tile
#pragma unroll
                    for (int r = 0; r < 4; ++r)
                        if (n < quad*4 + r) zacc[rt][r] += exp2f(d[r] * CEXP);
                } else {
#pragma unroll
                    for (int r = 0; r < 4; ++r) zacc[rt][r] += exp2f(d[r] * CEXP);
                }
            }
        }

        // reduce over the 16 col lanes of each quad, then one atomic per row
#pragma unroll
        for (int rt = 0; rt < 4; ++rt)
#pragma unroll
            for (int r = 0; r < 4; ++r) {
                float z = zacc[rt][r];
                z += __shfl_xor(z, 1); z += __shfl_xor(z, 2);
                z += __shfl_xor(z, 4); z += __shfl_xor(z, 8);
                if (n == 0)
                    atomicAdd(&Zbuf[nhL + qt*64 + rt*16 + quad*4 + r], z);
            }
    }
}

// ---------------------------------------------------------------------------
// K2b: finalize invZ and diag_s from Zbuf + ediag.
// ---------------------------------------------------------------------------
__global__ __launch_bounds__(256) void zfin_kernel(
    const float* __restrict__ Zbuf, const float* __restrict__ ediag,
    float* __restrict__ invZ, float* __restrict__ diag_s)
{
    const int i = blockIdx.x * 256 + threadIdx.x;
    const float de = exp2f(ediag[i] * CEXP);
    const float iz = 1.f / (Zbuf[i] + de);
    invZ[i]   = iz;
    diag_s[i] = de * iz;
}

// ---------------------------------------------------------------------------
// K3: partial colsum[l] = sum_{q>l} exp(e[q,l]/32)*invZ[q], load-balanced
// the same way: pair p handles l-tiles {p, 31-p}; residue-class split over
// q-16-tiles; fp32 atomics into colsum.
// ---------------------------------------------------------------------------
__global__ __launch_bounds__(256) void colsum_part(
    const unsigned short* __restrict__ qb, const unsigned short* __restrict__ okb,
    const float* __restrict__ invZ, float* __restrict__ colsum)
{
    const int px = blockIdx.x;
    const int pair = px >> 2;
    const int s = px & 3;
    const int nh = blockIdx.y;
    const int t = threadIdx.x;
    const int w = t >> 6;
    const int lane = t & 63;
    const int n = lane & 15;
    const int quad = lane >> 4;
    const size_t base = (size_t)nh * (LL * 64);
    const size_t nhL = (size_t)nh * LL;
    const int r0 = 4 * s + w;     // residue 0..15

#pragma unroll
    for (int half = 0; half < 2; ++half) {
        const int lt = half ? (31 - pair) : pair;

        bf16x8 bl[4][2];
#pragma unroll
        for (int ct = 0; ct < 4; ++ct) {
            const unsigned short* p = okb + base + (size_t)(lt*64 + ct*16 + n) * 64 + quad * 8;
            bl[ct][0] = ldfrag(p); bl[ct][1] = ldfrag(p + 32);
        }

        float cacc[4] = {0.f, 0.f, 0.f, 0.f};

        const int kstart = 4*lt + r0;
        bf16x8 a0c, a1c; float izc = 0.f;
        if (kstart < KT16) {
            const unsigned short* qp = qb + base + (size_t)(kstart*16 + n) * 64 + quad * 8;
            a0c = ldfrag(qp); a1c = ldfrag(qp + 32);
            izc = invZ[nhL + kstart*16 + n];
        }
        for (int kt = kstart; kt < KT16; kt += 16) {
            bf16x8 a0 = a0c, a1 = a1c; const float izq = izc;
            if (kt + 16 < KT16) {
                const unsigned short* qp = qb + base + (size_t)((kt+16)*16 + n) * 64 + quad * 8;
                a0c = ldfrag(qp); a1c = ldfrag(qp + 32);
                izc = invZ[nhL + (kt+16)*16 + n];
            }
            float izr[4];
#pragma unroll
            for (int r = 0; r < 4; ++r) izr[r] = __shfl(izq, quad*4 + r);
            const int dk = kt - 4*lt;   // >=0 by construction
#pragma unroll
            for (int ct = 0; ct < 4; ++ct) {
                if (ct > dk) continue;                    // empty (q < l)
                f32x4 d = {0.f,0.f,0.f,0.f};
                d = __builtin_amdgcn_mfma_f32_16x16x32_bf16(a0, bl[ct][0], d, 0,0,0);
                d = __builtin_amdgcn_mfma_f32_16x16x32_bf16(a1, bl[ct][1], d, 0,0,0);
                if (ct == dk) {                            // diagonal tile: q>l only
#pragma unroll
                    for (int r = 0; r < 4; ++r)
                        if (quad*4 + r > n) cacc[ct] += exp2f(d[r] * CEXP) * izr[r];
                } else {
#pragma unroll
                    for (int r = 0; r < 4; ++r) cacc[ct] += exp2f(d[r] * CEXP) * izr[r];
                }
            }
        }

#pragma unroll
        for (int ct = 0; ct < 4; ++ct) {
            float c = cacc[ct];
            c += __shfl_down(c, 32);
            c += __shfl_down(c, 16);
            if (lane < 16)
                atomicAdd(&colsum[nhL + lt*64 + ct*16 + lane], c);
        }
    }
}

// ---------------------------------------------------------------------------
// K4: fc_w -> bf16
// ---------------------------------------------------------------------------
__global__ __launch_bounds__(256) void fcw_kernel(
    const float* __restrict__ fc_w, unsigned short* __restrict__ fcwb)
{
    const int idx = blockIdx.x * 1024 + threadIdx.x * 4;
    float4 wv = *reinterpret_cast<const float4*>(fc_w + idx);
    ushort4 o;
    o.x = f2bf(wv.x); o.y = f2bf(wv.y); o.z = f2bf(wv.z); o.w = f2bf(wv.w);
    *reinterpret_cast<ushort4*>(fcwb + idx) = o;
}

// ---------------------------------------------------------------------------
// K5: attb[row][d] = bf16( diag_s*vb + colsum*ovb )
// ---------------------------------------------------------------------------
__global__ __launch_bounds__(256) void att_kernel(
    const unsigned short* __restrict__ vb, const unsigned short* __restrict__ ovb,
    const float* __restrict__ diag_s, const float* __restrict__ colsum,
    unsigned short* __restrict__ attb)
{
    const int row = blockIdx.x;            // n*L + l
    const int nn = row >> 11, l = row & 2047;
    const int t = threadIdx.x;
    const int d0 = t * 4;
    const int h = t >> 4;                  // d0>>6
    const size_t nhl = ((size_t)(nn * HH + h)) * LL + l;
    const float ds = diag_s[nhl];
    const float cs = colsum[nhl];
    const ushort4 v  = *reinterpret_cast<const ushort4*>(vb  + (size_t)row * DD + d0);
    const ushort4 ov = *reinterpret_cast<const ushort4*>(ovb + (size_t)row * DD + d0);
    ushort4 o;
    o.x = f2bf(ds * bf2f(v.x) + cs * bf2f(ov.x));
    o.y = f2bf(ds * bf2f(v.y) + cs * bf2f(ov.y));
    o.z = f2bf(ds * bf2f(v.z) + cs * bf2f(ov.z));
    o.w = f2bf(ds * bf2f(v.w) + cs * bf2f(ov.w));
    *reinterpret_cast<ushort4*>(attb + (size_t)row * DD + d0) = o;
}

// ---------------------------------------------------------------------------
// K6: out = attb @ fcwb^T + fc_b, bf16 MFMA GEMM, register-pipelined.
// ---------------------------------------------------------------------------
__global__ __launch_bounds__(256) void out_kernel(
    const unsigned short* __restrict__ attb, const unsigned short* __restrict__ fcwb,
    const float* __restrict__ fc_b, float* __restrict__ out)
{
    const int ct = blockIdx.x;   // 0..15  col tile (64 cols)
    const int rt = blockIdx.y;   // 0..31  row tile (128 rows)
    const int t = threadIdx.x;
    const int w = t >> 6;
    const int lane = t & 63;
    const int n = lane & 15;
    const int quad = lane >> 4;

    const int row0 = rt * 128 + w * 32;
    const int col0 = ct * 64;

    const unsigned short* ap = attb + (size_t)(row0 + n) * DD + quad * 8;
    const unsigned short* bp = fcwb + (size_t)(col0 + n) * DD + quad * 8;

    f32x4 acc[2][4];
#pragma unroll
    for (int i = 0; i < 2; ++i)
#pragma unroll
        for (int j = 0; j < 4; ++j) acc[i][j] = (f32x4){0.f, 0.f, 0.f, 0.f};

    bf16x8 a[2][2], b[2][4];
    a[0][0] = ldfrag(ap);
    a[0][1] = ldfrag(ap + 16 * DD);
#pragma unroll
    for (int j = 0; j < 4; ++j) b[0][j] = ldfrag(bp + (size_t)(j * 16) * DD);

    int cur = 0;
    for (int kc = 0; kc < DD; kc += 32) {
        const int nxt = cur ^ 1;
        if (kc + 32 < DD) {
            a[nxt][0] = ldfrag(ap + kc + 32);
            a[nxt][1] = ldfrag(ap + 16 * DD + kc + 32);
#pragma unroll
            for (int j = 0; j < 4; ++j)
                b[nxt][j] = ldfrag(bp + (size_t)(j * 16) * DD + kc + 32);
        }
#pragma unroll
        for (int i = 0; i < 2; ++i)
#pragma unroll
            for (int j = 0; j < 4; ++j)
                acc[i][j] = __builtin_amdgcn_mfma_f32_16x16x32_bf16(
                    a[cur][i], b[cur][j], acc[i][j], 0, 0, 0);
        cur = nxt;
    }

#pragma unroll
    for (int j = 0; j < 4; ++j) {
        const int col = col0 + j * 16 + n;
        const float bias = fc_b[col];
#pragma unroll
        for (int i = 0; i < 2; ++i)
#pragma unroll
            for (int r = 0; r < 4; ++r) {
                const int grow = row0 + i * 16 + quad * 4 + r;
                out[(size_t)grow * DD + col] = acc[i][j][r] + bias;
            }
    }
}

// ---------------------------------------------------------------------------
extern "C" void kernel_launch(void* const* d_in, const int* in_sizes, int n_in,
                              void* d_out, int out_size, void* d_ws, size_t ws_size,
                              hipStream_t stream) {
    const float* values = (const float*)d_in[0];
    const float* keys   = (const float*)d_in[1];
    const float* query  = (const float*)d_in[2];
    const float* ovals  = (const float*)d_in[3];
    const float* okeys  = (const float*)d_in[4];
    const float* Wv     = (const float*)d_in[5];
    const float* Wk     = (const float*)d_in[6];
    const float* Wq     = (const float*)d_in[7];
    const float* fc_w   = (const float*)d_in[8];
    const float* fc_b   = (const float*)d_in[9];
    // d_in[10]: mask — HIST==L makes it pure causal, handled analytically.
    float* out = (float*)d_out;

    float* ws      = (float*)d_ws;
    float* ediag   = ws;                     // 65536 f32
    float* Zbuf    = ediag + 65536;          // 65536 f32 (atomic accum)
    float* colsum  = Zbuf + 65536;           // 65536 f32 (atomic accum)
    float* invZ    = colsum + 65536;
    float* diag_s  = invZ + 65536;
    unsigned short* qb   = (unsigned short*)(diag_s + 65536);  // [32][2048][64] bf16
    unsigned short* okb  = qb   + 4194304;
    unsigned short* vb   = okb  + 4194304;   // [n][l][1024] bf16
    unsigned short* ovb  = vb   + 4194304;
    unsigned short* attb = ovb  + 4194304;   // [4096][1024] bf16
    unsigned short* fcwb = attb + 4194304;   // [1024][1024] bf16

    // zero the two atomic accumulators (Zbuf, colsum are adjacent)
    hipMemsetAsync(Zbuf, 0, 2 * 65536 * sizeof(float), stream);

    proj_kernel<<<dim3(64, 8), 256, 0, stream>>>(
        values, keys, query, ovals, okeys, Wv, Wk, Wq, qb, okb, vb, ovb, ediag);
    fcw_kernel<<<dim3(1024), 256, 0, stream>>>(fc_w, fcwb);
    zrow_part<<<dim3(64, NHH), 256, 0, stream>>>(qb, okb, Zbuf);
    zfin_kernel<<<dim3(256), 256, 0, stream>>>(Zbuf, ediag, invZ, diag_s);
    colsum_part<<<dim3(64, NHH), 256, 0, stream>>>(qb, okb, invZ, colsum);
    att_kernel<<<dim3(NB * LL), 256, 0, stream>>>(vb, ovb, diag_s, colsum, attb);
    out_kernel<<<dim3(16, 32), 256, 0, stream>>>(attb, fcwb, fc_b, out);
}